// Round 18
// baseline (349.394 us; speedup 1.0000x reference)
//
#include <hip/hip_runtime.h>

typedef __attribute__((ext_vector_type(2))) long lx2;
typedef __attribute__((ext_vector_type(4))) float f32x4;

__device__ __forceinline__ ushort f2bf(float f) {
  union { float f; unsigned u; } x; x.f = f;
  unsigned r = x.u + 0x7FFFu + ((x.u >> 16) & 1u);
  return (ushort)(r >> 16);
}
__device__ __forceinline__ float bf2f(ushort u) {
  union { unsigned u; float f; } x; x.u = ((unsigned)u) << 16;
  return x.f;
}

// ---------------- fp8 e4m3 encode/decode ----------------
#if defined(__has_builtin)
#if __has_builtin(__builtin_amdgcn_cvt_pk_fp8_f32) && __has_builtin(__builtin_amdgcn_cvt_f32_fp8)
#define HAVE_HW_FP8 1
#endif
#endif

#ifdef HAVE_HW_FP8
__device__ __forceinline__ uint pk4_fp8(float f0, float f1, float f2, float f3) {
  int r = __builtin_amdgcn_cvt_pk_fp8_f32(f0, f1, 0, false);
  r = __builtin_amdgcn_cvt_pk_fp8_f32(f2, f3, r, true);
  return (uint)r;
}
#define FP8DEC(dw, sel) __builtin_amdgcn_cvt_f32_fp8((int)(dw), (sel))
#else
// software OCP e4m3fn: value = (8+M)*2^(E-10) for E>=1; M*2^-9 subnormal; max 448.
__device__ __forceinline__ unsigned char f2e4m3(float f) {
  unsigned u = __float_as_uint(f);
  unsigned s = (u >> 24) & 0x80;
  float a = fabsf(f);
  if (a != a) return (unsigned char)(s | 0x7f);
  if (a >= 448.f) return (unsigned char)(s | 0x7e);
  int ei;
  (void)frexpf(a, &ei);
  int E = ei + 6;
  if (E < 1) {
    int ki = (int)rintf(a * 512.f);
    if (ki >= 8) return (unsigned char)(s | 0x08);
    return (unsigned char)(s | ki);
  }
  float q = a * exp2f((float)(10 - E));
  int ki = (int)rintf(q);
  if (ki >= 16) { E++; ki = 8; }
  if (E > 15 || (E == 15 && ki > 14)) return (unsigned char)(s | 0x7e);
  return (unsigned char)(s | (E << 3) | (ki - 8));
}
__device__ __forceinline__ uint pk4_fp8(float f0, float f1, float f2, float f3) {
  return (uint)f2e4m3(f0) | ((uint)f2e4m3(f1) << 8) |
         ((uint)f2e4m3(f2) << 16) | ((uint)f2e4m3(f3) << 24);
}
__device__ __forceinline__ float e4m3dec(unsigned char b) {
  int E = (b >> 3) & 15, M = b & 7;
  float v = E ? ldexpf((float)(8 + M), E - 10) : ldexpf((float)M, -9);
  return (b & 0x80) ? -v : v;
}
#define FP8DEC(dw, sel) e4m3dec((unsigned char)(((dw) >> (8 * (sel))) & 0xff))
#endif

__device__ __forceinline__ void gload_lds16(const void* g, void* l) {
  __builtin_amdgcn_global_load_lds(
      (const __attribute__((address_space(1))) void*)g,
      (__attribute__((address_space(3))) void*)l, 16, 0, 0);
}

// ------- fp32 -> fp8 (weights only), wave owns 1024 contiguous elems -------
__global__ __launch_bounds__(256) void cvt3_fp8(
    const float* __restrict__ s0, const float* __restrict__ s1,
    const float* __restrict__ s2, uint* __restrict__ d0,
    uint* __restrict__ d1, uint* __restrict__ d2, long n) {
  const float* s = blockIdx.y == 0 ? s0 : (blockIdx.y == 1 ? s1 : s2);
  uint* d = blockIdx.y == 0 ? d0 : (blockIdx.y == 1 ? d1 : d2);
  const int lane = threadIdx.x & 63;
  const int w = threadIdx.x >> 6;
  const long wave_base = ((long)blockIdx.x * 4 + w) * 1024;
  if (wave_base >= n) return;
  float4 f[4];
#pragma unroll
  for (int j = 0; j < 4; ++j)
    f[j] = *(const float4*)(s + wave_base + j * 256 + lane * 4);
#pragma unroll
  for (int j = 0; j < 4; ++j)
    d[(wave_base >> 2) + j * 64 + lane] = pk4_fp8(f[j].x, f[j].y, f[j].z, f[j].w);
}

// ============ 256x256 16-wave fp8 GEMM (B^T form), 1 barrier / K-tile ============
// C[m,n] = f((sum_k A[m,k]*B[n,k])*(SCALED?scale:1) + bias), f=exp if EXPOUT
// 1024 thr = 16 waves (4m x 4n), per-wave 64x64 (acc[4][4]). BK=64. LDS 64KB dbuf.
// Chunk r (rows r*16..+15, 64 k), lane-major: lane l = (row r*16+(l&15), 16 k's).
// PF32: 0 none; 1 A operand is fp32 in global, reg-staged (load post-barrier,
//   cvt+ds_write at next tile top); 2 same for B. Fuses the fp32->fp8 convert
//   into the GEMM -- no separate cvt kernel / fp8 round trip for q,k,v.
// Per K-tile: { vmcnt(0) [F gloads + P reg loads landed] | [PWRITE + lgkm0] |
//   bar | stage t+1 (F gload + P loads) | 8 ds_read | lgkm0 | 32 MFMA }.
// Epilogue: C staged to LDS bf16 (XOR 32B-slot swizzle), coalesced flush;
// OUT_FP8 converts on flush. REDUCE: 1 col max+sumexp; 2 col plain-sum.
template<int BIAS_MODE, int SCALED, int REDUCE, int EXPOUT, int OUT_FP8, int PF32>
__global__ __launch_bounds__(1024, 4) void gemmF(
    const void* __restrict__ Av, const void* __restrict__ Bv,
    void* __restrict__ Cv, const float* __restrict__ bias,
    float* __restrict__ red_max, float* __restrict__ red_sum,
    int N, int K, long sA, long sB, long sC, float scale, int gm, int gn)
{
  extern __shared__ unsigned char lds[];   // 65536 B

  // ---- tile decode: bijective XCD swizzle + banded order ----
  const int nwg = gridDim.x;
  const int wg = blockIdx.x;
  const int cpx = nwg >> 3;
  const int wid_ = (wg & 7) * cpx + (wg >> 3);
  const int tiles = gm * gn;
  const int bz = wid_ / tiles;
  const int t2 = wid_ - bz * tiles;
  const int band = t2 / (gm << 2);
  const int r2 = t2 - band * (gm << 2);
  const int tile_m = (r2 >> 2) * 256;
  const int tile_n = ((band << 2) + (r2 & 3)) * 256;

  const unsigned char* Ab8 = (PF32 == 1) ? nullptr : (const unsigned char*)Av + (size_t)bz * sA;
  const float*         AbF = (PF32 == 1) ? (const float*)Av + (size_t)bz * sA : nullptr;
  const unsigned char* Bb8 = (PF32 == 2) ? nullptr : (const unsigned char*)Bv + (size_t)bz * sB;
  const float*         BbF = (PF32 == 2) ? (const float*)Bv + (size_t)bz * sB : nullptr;

  const int t = threadIdx.x;
  const int lane = t & 63;
  const int w = t >> 6;        // 0..15
  const int wr = w >> 2;       // 0..3
  const int wc = w & 3;        // 0..3

  f32x4 acc[4][4] = {};
  float4 R[4];                 // PF32 staging regs (16 fp32 = one lane's 16 k's)

#define STAGE_FA(c, k0)                                                                \
    gload_lds16(Ab8 + (size_t)(tile_m + w * 16 + (lane & 15)) * K + (k0) +             \
                    (lane >> 4) * 16,                                                  \
                lds + (c) * 32768 + w * 1024)
#define STAGE_FB(c, k0)                                                                \
    gload_lds16(Bb8 + (size_t)(tile_n + w * 16 + (lane & 15)) * K + (k0) +             \
                    (lane >> 4) * 16,                                                  \
                lds + (c) * 32768 + 16384 + w * 1024)
#define PLOAD(PbF, tile_p, k0)                                                         \
  do {                                                                                 \
    const float* pp = (PbF) + (size_t)((tile_p) + w * 16 + (lane & 15)) * K +          \
                      (k0) + (lane >> 4) * 16;                                         \
    R[0] = *(const float4*)(pp);      R[1] = *(const float4*)(pp + 4);                 \
    R[2] = *(const float4*)(pp + 8);  R[3] = *(const float4*)(pp + 12);                \
  } while (0)
#define PWRITE(c, roff)                                                                \
  do {                                                                                 \
    uint4 o;                                                                           \
    o.x = pk4_fp8(R[0].x, R[0].y, R[0].z, R[0].w);                                     \
    o.y = pk4_fp8(R[1].x, R[1].y, R[1].z, R[1].w);                                     \
    o.z = pk4_fp8(R[2].x, R[2].y, R[2].z, R[2].w);                                     \
    o.w = pk4_fp8(R[3].x, R[3].y, R[3].z, R[3].w);                                     \
    *(uint4*)(lds + (c) * 32768 + (roff) + w * 1024 + lane * 16) = o;                  \
  } while (0)

  // ---- prologue: tile 0 ----
  if constexpr (PF32 == 1) { STAGE_FB(0, 0); PLOAD(AbF, tile_m, 0); }
  else if constexpr (PF32 == 2) { STAGE_FA(0, 0); PLOAD(BbF, tile_n, 0); }
  else { STAGE_FA(0, 0); STAGE_FB(0, 0); }

  const int KT = K >> 6;
  for (int tt = 0; tt < KT; ++tt) {
    const int c = tt & 1;
    asm volatile("s_waitcnt vmcnt(0)" ::: "memory");   // F gloads + P reg loads landed
    if constexpr (PF32 == 1) {
      PWRITE(c, 0);
      asm volatile("s_waitcnt lgkmcnt(0)" ::: "memory");
    } else if constexpr (PF32 == 2) {
      PWRITE(c, 16384);
      asm volatile("s_waitcnt lgkmcnt(0)" ::: "memory");
    }
    __builtin_amdgcn_s_barrier();                      // publish all waves' stages
    if (tt + 1 < KT) {
      const int k0n = (tt + 1) << 6;
      if constexpr (PF32 == 1) { STAGE_FB(c ^ 1, k0n); PLOAD(AbF, tile_m, k0n); }
      else if constexpr (PF32 == 2) { STAGE_FA(c ^ 1, k0n); PLOAD(BbF, tile_n, k0n); }
      else { STAGE_FA(c ^ 1, k0n); STAGE_FB(c ^ 1, k0n); }
    }
    lx2 aA[4], bB[4];
#pragma unroll
    for (int mi = 0; mi < 4; ++mi)
      aA[mi] = *(const lx2*)(lds + c * 32768 + (wr * 4 + mi) * 1024 + lane * 16);
#pragma unroll
    for (int nf = 0; nf < 4; ++nf)
      bB[nf] = *(const lx2*)(lds + c * 32768 + 16384 + (wc * 4 + nf) * 1024 + lane * 16);
    asm volatile("s_waitcnt lgkmcnt(0)" ::: "memory");
    __builtin_amdgcn_sched_barrier(0);
    __builtin_amdgcn_s_setprio(1);
#pragma unroll
    for (int kk = 0; kk < 2; ++kk)
#pragma unroll
      for (int mi = 0; mi < 4; ++mi)
#pragma unroll
        for (int nf = 0; nf < 4; ++nf)
          acc[mi][nf] = __builtin_amdgcn_mfma_f32_16x16x32_fp8_fp8(
              aA[mi][kk], bB[nf][kk], acc[mi][nf], 0, 0, 0);
    __builtin_amdgcn_s_setprio(0);
  }
#undef STAGE_FA
#undef STAGE_FB
#undef PLOAD
#undef PWRITE

  // ---- epilogue: 2 half-passes (128 rows) via LDS bf16, swizzled ----
  float sm2[4] = {0.f, 0.f, 0.f, 0.f};
  const int g5 = ((lane >> 4) & 3) << 5;
  int ccl[4]; float bcn[4];
#pragma unroll
  for (int nf = 0; nf < 4; ++nf) {
    ccl[nf] = wc * 64 + nf * 16 + (lane & 15);
    bcn[nf] = (BIAS_MODE == 1) ? bias[tile_n + ccl[nf]] : 0.f;
  }
#pragma unroll
  for (int h = 0; h < 2; ++h) {
    __syncthreads();
    if ((wr >> 1) == h) {
#pragma unroll
      for (int mi = 0; mi < 4; ++mi) {
#pragma unroll
        for (int j = 0; j < 4; ++j) {
          const int row = (wr & 1) * 64 + mi * 16 + ((lane >> 4) << 2) + j;  // 0..127
          float bcr = (BIAS_MODE == 2) ? bias[tile_m + h * 128 + row] : 0.f;
#pragma unroll
          for (int nf = 0; nf < 4; ++nf) {
            float val = acc[mi][nf][j];
            if (SCALED) val *= scale;
            if (BIAS_MODE == 1) val += bcn[nf];
            else if (BIAS_MODE == 2) val += bcr;
            if (EXPOUT) val = __expf(val);
            if (REDUCE == 2) sm2[nf] += val;
            *(ushort*)(lds + row * 512 + ((ccl[nf] * 2) ^ g5)) = f2bf(val);
          }
        }
      }
    }
    __syncthreads();
    // coalesced flush: 4 passes x 1024 thr x 16B LDS
#pragma unroll
    for (int p = 0; p < 4; ++p) {
      int off = p * 16384 + t * 16;
      int row = off >> 9;
      int b = off & 511;
      int bs = b ^ (((row >> 2) & 3) << 5);
      f32x4 d = *(const f32x4*)(lds + row * 512 + bs);
      const int gr = tile_m + h * 128 + row;
      if (OUT_FP8) {
        const uint* dw = (const uint*)&d;
        float f0 = bf2f((ushort)(dw[0] & 0xffff)), f1 = bf2f((ushort)(dw[0] >> 16));
        float f2 = bf2f((ushort)(dw[1] & 0xffff)), f3 = bf2f((ushort)(dw[1] >> 16));
        float f4 = bf2f((ushort)(dw[2] & 0xffff)), f5 = bf2f((ushort)(dw[2] >> 16));
        float f6 = bf2f((ushort)(dw[3] & 0xffff)), f7 = bf2f((ushort)(dw[3] >> 16));
        uint2 o;
        o.x = pk4_fp8(f0, f1, f2, f3);
        o.y = pk4_fp8(f4, f5, f6, f7);
        *(uint2*)((unsigned char*)Cv + (size_t)bz * sC + (size_t)gr * N + tile_n + (b >> 1)) = o;
      } else {
        *(f32x4*)((ushort*)Cv + (size_t)bz * sC + (size_t)gr * N + tile_n + (b >> 1)) = d;
      }
    }
  }

  if constexpr (REDUCE == 2) {
    __syncthreads();
    float* sb = (float*)lds;   // [4][256]
#pragma unroll
    for (int nf = 0; nf < 4; ++nf) {
      float s1 = sm2[nf] + __shfl_xor(sm2[nf], 16);
      float Ss = s1 + __shfl_xor(s1, 32);
      if ((lane >> 4) == nf) sb[wr * 256 + ccl[nf]] = Ss;
    }
    __syncthreads();
    if (t < 256) {
      size_t rb = ((size_t)bz * gm + (tile_m >> 8)) * N + tile_n + t;
      red_sum[rb] = sb[t] + sb[256 + t] + sb[512 + t] + sb[768 + t];
    }
  }
  if constexpr (REDUCE == 1) {
    __syncthreads();
    float* mb = (float*)lds;          // [4][256]
    float* sb = (float*)lds + 1024;   // [4][256]
#pragma unroll
    for (int nf = 0; nf < 4; ++nf) {
      float mx = -1e30f;
#pragma unroll
      for (int mi = 0; mi < 4; ++mi)
#pragma unroll
        for (int j = 0; j < 4; ++j) {
          float val = acc[mi][nf][j];
          if (SCALED) val *= scale;
          mx = fmaxf(mx, val);
        }
      float m1 = fmaxf(mx, __shfl_xor(mx, 16));
      float M = fmaxf(m1, __shfl_xor(m1, 32));
      float sm = 0.f;
#pragma unroll
      for (int mi = 0; mi < 4; ++mi)
#pragma unroll
        for (int j = 0; j < 4; ++j) {
          float val = acc[mi][nf][j];
          if (SCALED) val *= scale;
          sm += __expf(val - M);
        }
      float s1 = sm + __shfl_xor(sm, 16);
      float Ss = s1 + __shfl_xor(s1, 32);
      if ((lane >> 4) == nf) {
        mb[wr * 256 + ccl[nf]] = M;
        sb[wr * 256 + ccl[nf]] = Ss;
      }
    }
    __syncthreads();
    if (t < 256) {
      float M = fmaxf(fmaxf(mb[t], mb[256 + t]), fmaxf(mb[512 + t], mb[768 + t]));
      float Ss = sb[t] * __expf(mb[t] - M) + sb[256 + t] * __expf(mb[256 + t] - M) +
                 sb[512 + t] * __expf(mb[512 + t] - M) + sb[768 + t] * __expf(mb[768 + t] - M);
      size_t rb = ((size_t)bz * gm + (tile_m >> 8)) * N + tile_n + t;
      red_max[rb] = M;
      red_sum[rb] = Ss;
    }
  }
}

// c[b,k] = 1024 / sum_ch red_sum[b][ch][k]   (x1024 keeps vs in fp8 range)
__global__ __launch_bounds__(256) void combine_c(
    const float* __restrict__ red_sum, float* __restrict__ cvec, int cols, int nch)
{
  const int b = blockIdx.y;
  const int c = blockIdx.x * 256 + threadIdx.x;
  float Z = 0.f;
  for (int ch = 0; ch < nch; ++ch)
    Z += red_sum[((size_t)b * nch + ch) * cols + c];
  cvec[(size_t)b * cols + c] = 1024.f / Z;
}

// vs[b][d][k] = fp8( vpT_fp8[b][d][k] * c[b][k] )   (8 elems/thread)
__global__ __launch_bounds__(256) void scale_v(
    const uint2* __restrict__ vpT, const float* __restrict__ cvec,
    uint2* __restrict__ vs, int S, long DS)
{
  const size_t i8 = (size_t)blockIdx.x * 256 + threadIdx.x;
  const size_t k8 = i8 * 8;
  const int b = (int)(k8 / DS);
  const int kcol = (int)(k8 % S);
  uint2 u = vpT[i8];
  const float* cb = cvec + (size_t)b * S + kcol;
  float f0 = FP8DEC(u.x, 0) * cb[0], f1 = FP8DEC(u.x, 1) * cb[1];
  float f2 = FP8DEC(u.x, 2) * cb[2], f3 = FP8DEC(u.x, 3) * cb[3];
  float f4 = FP8DEC(u.y, 0) * cb[4], f5 = FP8DEC(u.y, 1) * cb[5];
  float f6 = FP8DEC(u.y, 2) * cb[6], f7 = FP8DEC(u.y, 3) * cb[7];
  uint2 o;
  o.x = pk4_fp8(f0, f1, f2, f3);
  o.y = pk4_fp8(f4, f5, f6, f7);
  vs[i8] = o;
}

// combine partials -> M, 1/Z per (b,col). grid: (cols/256, B)
__global__ __launch_bounds__(256) void colsm_combine(
    const float* __restrict__ red_max, const float* __restrict__ red_sum,
    float* __restrict__ Mv, float* __restrict__ Zinv, int cols, int nch)
{
  const int b = blockIdx.y;
  const int c = blockIdx.x * 256 + threadIdx.x;
  float M = -1e30f, Z = 0.f;
  for (int ch = 0; ch < nch; ++ch) {
    size_t o = ((size_t)b * nch + ch) * cols + c;
    float m = red_max[o], s = red_sum[o];
    float nm = fmaxf(M, m);
    Z = Z * __expf(M - nm) + s * __expf(m - nm);
    M = nm;
  }
  Mv[(size_t)b * cols + c] = M;
  Zinv[(size_t)b * cols + c] = 1.f / Z;
}

// final: out1 = softmax(attn over rows), out0 = attn + residual. attn is bf16.
__global__ __launch_bounds__(256) void final_emit(
    const ushort* __restrict__ attnB, const float* __restrict__ q,
    float* __restrict__ out0, float* __restrict__ out1,
    const float* __restrict__ Mv, const float* __restrict__ Zinv,
    int rows, int cols, int rpc)
{
  const int b = blockIdx.y;
  const int ch = blockIdx.z;
  const size_t base = (size_t)b * rows * cols;
  const int c4 = (blockIdx.x * 256 + threadIdx.x) * 4;
  const int r0 = ch * rpc;
  float M[4], Zi[4];
#pragma unroll
  for (int i = 0; i < 4; ++i) {
    M[i] = Mv[(size_t)b * cols + c4 + i];
    Zi[i] = Zinv[(size_t)b * cols + c4 + i];
  }
  for (int r = r0; r < r0 + rpc; ++r) {
    size_t o = base + (size_t)r * cols + c4;
    ushort4 u = *(const ushort4*)(attnB + o);
    float4 qv = *(const float4*)(q + o);
    float a0 = bf2f(u.x), a1 = bf2f(u.y), a2 = bf2f(u.z), a3 = bf2f(u.w);
    float4 wv, s;
    wv.x = __expf(a0 - M[0]) * Zi[0];
    wv.y = __expf(a1 - M[1]) * Zi[1];
    wv.z = __expf(a2 - M[2]) * Zi[2];
    wv.w = __expf(a3 - M[3]) * Zi[3];
    s.x = a0 + qv.x; s.y = a1 + qv.y; s.z = a2 + qv.z; s.w = a3 + qv.w;
    *(float4*)(out1 + o) = wv;
    *(float4*)(out0 + o) = s;
  }
}

extern "C" void kernel_launch(void* const* d_in, const int* in_sizes, int n_in,
                              void* d_out, int out_size, void* d_ws, size_t ws_size,
                              hipStream_t stream) {
  const float* q  = (const float*)d_in[0];
  const float* k  = (const float*)d_in[1];
  const float* v  = (const float*)d_in[2];
  const float* Wq = (const float*)d_in[3];
  const float* bq = (const float*)d_in[4];
  const float* Wk = (const float*)d_in[5];
  const float* bk = (const float*)d_in[6];
  const float* Wv = (const float*)d_in[7];
  const float* bv = (const float*)d_in[8];
  float* out = (float*)d_out;

  const int B = 8, S = 2048, D = 1024;
  const long BS = (long)B * S;
  const long nQKV = BS * D;
  const long nW = (long)D * D;

  // d_out: Wq8/Wk8/Wv8 fp8 @0/1/2MB; red_s_sum @64M; c_s @66M.
  // final_emit overwrites all of d_out at the end.
  unsigned char* Wq8 = (unsigned char*)d_out;
  unsigned char* Wk8 = Wq8 + nW;
  unsigned char* Wv8 = Wk8 + nW;
  float* red_s_sum = (float*)((char*)d_out + (64ull << 20));
  float* c_s       = (float*)((char*)d_out + (66ull << 20));

  // ws: qp8 [0,16M), kp8 [16,32M), vpT8 [32,48M), vs8 [48,64M),
  //     expS8 [64,96M), attnB bf16 [96,128M), red_f/Mf/Zf @128M+.
  char* ws = (char*)d_ws;
  unsigned char* qp8   = (unsigned char*)ws;
  unsigned char* kp8   = (unsigned char*)(ws + (16ull << 20));
  unsigned char* vpT8  = (unsigned char*)(ws + (32ull << 20));
  unsigned char* vs8   = (unsigned char*)(ws + (48ull << 20));
  unsigned char* expS8 = (unsigned char*)(ws + (64ull << 20));
  ushort* attnB        = (ushort*)(ws + (96ull << 20));
  float* red_f_max = (float*)(ws + (128ull << 20));
  float* red_f_sum = (float*)(ws + (129ull << 20));
  float* Mf        = (float*)(ws + (130ull << 20));
  float* Zf        = (float*)(ws + (131ull << 20));

  const int SH = 65536;
  (void)hipFuncSetAttribute(reinterpret_cast<const void*>(&gemmF<1,0,0,0,1,1>),
                            hipFuncAttributeMaxDynamicSharedMemorySize, SH);
  (void)hipFuncSetAttribute(reinterpret_cast<const void*>(&gemmF<2,0,0,0,1,2>),
                            hipFuncAttributeMaxDynamicSharedMemorySize, SH);
  (void)hipFuncSetAttribute(reinterpret_cast<const void*>(&gemmF<0,1,2,1,1,0>),
                            hipFuncAttributeMaxDynamicSharedMemorySize, SH);
  (void)hipFuncSetAttribute(reinterpret_cast<const void*>(&gemmF<0,1,1,0,0,0>),
                            hipFuncAttributeMaxDynamicSharedMemorySize, SH);

  // ---- fp32 -> fp8 conversion: weights only (3 MB) ----
  cvt3_fp8<<<dim3((unsigned)(nW / 4096), 3), 256, 0, stream>>>(
      Wq, Wk, Wv, (uint*)Wq8, (uint*)Wk8, (uint*)Wv8, nW);

  // qp[m][e] = q·Wq + bq (fp8 out); A = q fp32 reg-staged (fused cvt)
  gemmF<1,0,0,0,1,1><<<dim3(64 * 4), 1024, SH, stream>>>(
      q, Wq8, qp8, bq, nullptr, nullptr, D, D, 0, 0, 0, 1.f, 64, 4);
  gemmF<1,0,0,0,1,1><<<dim3(64 * 4), 1024, SH, stream>>>(
      k, Wk8, kp8, bk, nullptr, nullptr, D, D, 0, 0, 0, 1.f, 64, 4);
  // vpT[b][e][s] = Wv·v^T + bv (row bias, fp8 out); B = v fp32 reg-staged
  gemmF<2,0,0,0,1,2><<<dim3(4 * 8 * B), 1024, SH, stream>>>(
      Wv8, v, vpT8, bv, nullptr, nullptr, S, D, 0, (long)S * D, (long)D * S, 1.f, 4, 8);
  // expS = exp(qp·kp^T / 1024) (fp8 out) + fused col-sum partials
  gemmF<0,1,2,1,1,0><<<dim3(8 * 8 * B), 1024, SH, stream>>>(
      qp8, kp8, expS8, nullptr, nullptr, red_s_sum,
      S, D, (long)S * D, (long)S * D, (long)S * S, 1.f / 1024.f, 8, 8);

  // c = 1024/colsum;  vs = vpT * c  (fp8)
  combine_c<<<dim3(S / 256, B), 256, 0, stream>>>(red_s_sum, c_s, S, 8);
  scale_v<<<dim3((int)(nQKV / (256 * 8))), 256, 0, stream>>>(
      (const uint2*)vpT8, c_s, (uint2*)vs8, S, (long)D * S);

  // attn = (expS·vs^T)/1024 (bf16 out) + fused final-softmax pass1
  gemmF<0,1,1,0,0,0><<<dim3(8 * 4 * B), 1024, SH, stream>>>(
      expS8, vs8, attnB, nullptr, red_f_max, red_f_sum,
      D, S, (long)S * S, (long)D * S, (long)S * D, 1.f / 1024.f, 8, 4);

  colsm_combine<<<dim3(D / 256, B), 256, 0, stream>>>(red_f_max, red_f_sum, Mf, Zf, D, 8);
  final_emit<<<dim3(1, B, 128), 256, 0, stream>>>(attnB, q, out, out + nQKV, Mf, Zf, S, D, 16);

  (void)in_sizes; (void)n_in; (void)out_size; (void)ws_size;
}

// Round 19
// 341.993 us; speedup vs baseline: 1.0216x; 1.0216x over previous
//
#include <hip/hip_runtime.h>

typedef __attribute__((ext_vector_type(2))) long lx2;
typedef __attribute__((ext_vector_type(4))) float f32x4;

__device__ __forceinline__ ushort f2bf(float f) {
  union { float f; unsigned u; } x; x.f = f;
  unsigned r = x.u + 0x7FFFu + ((x.u >> 16) & 1u);
  return (ushort)(r >> 16);
}
__device__ __forceinline__ float bf2f(ushort u) {
  union { unsigned u; float f; } x; x.u = ((unsigned)u) << 16;
  return x.f;
}

// ---------------- fp8 e4m3 encode/decode ----------------
#if defined(__has_builtin)
#if __has_builtin(__builtin_amdgcn_cvt_pk_fp8_f32) && __has_builtin(__builtin_amdgcn_cvt_f32_fp8)
#define HAVE_HW_FP8 1
#endif
#endif

#ifdef HAVE_HW_FP8
__device__ __forceinline__ uint pk4_fp8(float f0, float f1, float f2, float f3) {
  int r = __builtin_amdgcn_cvt_pk_fp8_f32(f0, f1, 0, false);
  r = __builtin_amdgcn_cvt_pk_fp8_f32(f2, f3, r, true);
  return (uint)r;
}
#define FP8DEC(dw, sel) __builtin_amdgcn_cvt_f32_fp8((int)(dw), (sel))
#else
// software OCP e4m3fn: value = (8+M)*2^(E-10) for E>=1; M*2^-9 subnormal; max 448.
__device__ __forceinline__ unsigned char f2e4m3(float f) {
  unsigned u = __float_as_uint(f);
  unsigned s = (u >> 24) & 0x80;
  float a = fabsf(f);
  if (a != a) return (unsigned char)(s | 0x7f);
  if (a >= 448.f) return (unsigned char)(s | 0x7e);
  int ei;
  (void)frexpf(a, &ei);
  int E = ei + 6;
  if (E < 1) {
    int ki = (int)rintf(a * 512.f);
    if (ki >= 8) return (unsigned char)(s | 0x08);
    return (unsigned char)(s | ki);
  }
  float q = a * exp2f((float)(10 - E));
  int ki = (int)rintf(q);
  if (ki >= 16) { E++; ki = 8; }
  if (E > 15 || (E == 15 && ki > 14)) return (unsigned char)(s | 0x7e);
  return (unsigned char)(s | (E << 3) | (ki - 8));
}
__device__ __forceinline__ uint pk4_fp8(float f0, float f1, float f2, float f3) {
  return (uint)f2e4m3(f0) | ((uint)f2e4m3(f1) << 8) |
         ((uint)f2e4m3(f2) << 16) | ((uint)f2e4m3(f3) << 24);
}
__device__ __forceinline__ float e4m3dec(unsigned char b) {
  int E = (b >> 3) & 15, M = b & 7;
  float v = E ? ldexpf((float)(8 + M), E - 10) : ldexpf((float)M, -9);
  return (b & 0x80) ? -v : v;
}
#define FP8DEC(dw, sel) e4m3dec((unsigned char)(((dw) >> (8 * (sel))) & 0xff))
#endif

__device__ __forceinline__ void gload_lds16(const void* g, void* l) {
  __builtin_amdgcn_global_load_lds(
      (const __attribute__((address_space(1))) void*)g,
      (__attribute__((address_space(3))) void*)l, 16, 0, 0);
}

// ------- fp32 -> fp8 (weights only), wave owns 1024 contiguous elems -------
__global__ __launch_bounds__(256) void cvt3_fp8(
    const float* __restrict__ s0, const float* __restrict__ s1,
    const float* __restrict__ s2, uint* __restrict__ d0,
    uint* __restrict__ d1, uint* __restrict__ d2, long n) {
  const float* s = blockIdx.y == 0 ? s0 : (blockIdx.y == 1 ? s1 : s2);
  uint* d = blockIdx.y == 0 ? d0 : (blockIdx.y == 1 ? d1 : d2);
  const int lane = threadIdx.x & 63;
  const int w = threadIdx.x >> 6;
  const long wave_base = ((long)blockIdx.x * 4 + w) * 1024;
  if (wave_base >= n) return;
  float4 f[4];
#pragma unroll
  for (int j = 0; j < 4; ++j)
    f[j] = *(const float4*)(s + wave_base + j * 256 + lane * 4);
#pragma unroll
  for (int j = 0; j < 4; ++j)
    d[(wave_base >> 2) + j * 64 + lane] = pk4_fp8(f[j].x, f[j].y, f[j].z, f[j].w);
}

// ============ 256x256 16-wave fp8 GEMM (B^T form), 1 barrier / K-tile ============
// C[m,n] = f((sum_k A[m,k]*B[n,k])*(SCALED?scale:1) + bias), f=exp if EXPOUT
// 1024 thr = 16 waves (4m x 4n), per-wave 64x64 (acc[4][4]). BK=64. LDS 64KB dbuf.
// PF32: 0 none; 1 A is fp32 in global (reg-staged, fused cvt); 2 same for B.
// PF32 pipeline (2-deep, NO serialized write before barrier — round-18 fix):
//   iter tt: vmcnt(0) [F gload(tile tt) + PLOAD(tile tt+1) landed] | bar |
//            PWRITE(c^1, tile tt+1) | STAGE_F(c^1, tt+1) | PLOAD(tt+2) |
//            split ds_reads + 32 MFMA (first lgkm0 drains PWRITE early).
// PF32 reg budget: R[4](+16) offset by split A-frag reads aAh[2](-8).
// Epilogue: C staged to LDS bf16 (XOR 32B-slot swizzle), coalesced flush;
// OUT_FP8 converts on flush. REDUCE: 1 col max+sumexp; 2 col plain-sum.
template<int BIAS_MODE, int SCALED, int REDUCE, int EXPOUT, int OUT_FP8, int PF32>
__global__ __launch_bounds__(1024, 4) void gemmF(
    const void* __restrict__ Av, const void* __restrict__ Bv,
    void* __restrict__ Cv, const float* __restrict__ bias,
    float* __restrict__ red_max, float* __restrict__ red_sum,
    int N, int K, long sA, long sB, long sC, float scale, int gm, int gn)
{
  extern __shared__ unsigned char lds[];   // 65536 B

  // ---- tile decode: bijective XCD swizzle + banded order ----
  const int nwg = gridDim.x;
  const int wg = blockIdx.x;
  const int cpx = nwg >> 3;
  const int wid_ = (wg & 7) * cpx + (wg >> 3);
  const int tiles = gm * gn;
  const int bz = wid_ / tiles;
  const int t2 = wid_ - bz * tiles;
  const int band = t2 / (gm << 2);
  const int r2 = t2 - band * (gm << 2);
  const int tile_m = (r2 >> 2) * 256;
  const int tile_n = ((band << 2) + (r2 & 3)) * 256;

  const unsigned char* Ab8 = (PF32 == 1) ? nullptr : (const unsigned char*)Av + (size_t)bz * sA;
  const float*         AbF = (PF32 == 1) ? (const float*)Av + (size_t)bz * sA : nullptr;
  const unsigned char* Bb8 = (PF32 == 2) ? nullptr : (const unsigned char*)Bv + (size_t)bz * sB;
  const float*         BbF = (PF32 == 2) ? (const float*)Bv + (size_t)bz * sB : nullptr;

  const int t = threadIdx.x;
  const int lane = t & 63;
  const int w = t >> 6;        // 0..15
  const int wr = w >> 2;       // 0..3
  const int wc = w & 3;        // 0..3

  f32x4 acc[4][4] = {};
  float4 R[4];                 // PF32 staging regs (one lane's 16 k fp32)

#define STAGE_FA(c, k0)                                                                \
    gload_lds16(Ab8 + (size_t)(tile_m + w * 16 + (lane & 15)) * K + (k0) +             \
                    (lane >> 4) * 16,                                                  \
                lds + (c) * 32768 + w * 1024)
#define STAGE_FB(c, k0)                                                                \
    gload_lds16(Bb8 + (size_t)(tile_n + w * 16 + (lane & 15)) * K + (k0) +             \
                    (lane >> 4) * 16,                                                  \
                lds + (c) * 32768 + 16384 + w * 1024)
#define PLOAD(PbF, tile_p, k0)                                                         \
  do {                                                                                 \
    const float* pp = (PbF) + (size_t)((tile_p) + w * 16 + (lane & 15)) * K +          \
                      (k0) + (lane >> 4) * 16;                                         \
    R[0] = *(const float4*)(pp);      R[1] = *(const float4*)(pp + 4);                 \
    R[2] = *(const float4*)(pp + 8);  R[3] = *(const float4*)(pp + 12);                \
  } while (0)
#define PWRITE(c, roff)                                                                \
  do {                                                                                 \
    uint4 o;                                                                           \
    o.x = pk4_fp8(R[0].x, R[0].y, R[0].z, R[0].w);                                     \
    o.y = pk4_fp8(R[1].x, R[1].y, R[1].z, R[1].w);                                     \
    o.z = pk4_fp8(R[2].x, R[2].y, R[2].z, R[2].w);                                     \
    o.w = pk4_fp8(R[3].x, R[3].y, R[3].z, R[3].w);                                     \
    *(uint4*)(lds + (c) * 32768 + (roff) + w * 1024 + lane * 16) = o;                  \
  } while (0)

  const int KT = K >> 6;

  // ---- prologue: tile 0 (PF32: P chunk written via regs, then PLOAD tile 1) ----
  if constexpr (PF32 == 0) {
    STAGE_FA(0, 0); STAGE_FB(0, 0);
  } else if constexpr (PF32 == 1) {
    PLOAD(AbF, tile_m, 0);
    STAGE_FB(0, 0);
    asm volatile("s_waitcnt vmcnt(0)" ::: "memory");
    PWRITE(0, 0);
    asm volatile("s_waitcnt lgkmcnt(0)" ::: "memory");   // cross-wave vis at 1st bar
    if (KT > 1) PLOAD(AbF, tile_m, 64);
  } else {
    PLOAD(BbF, tile_n, 0);
    STAGE_FA(0, 0);
    asm volatile("s_waitcnt vmcnt(0)" ::: "memory");
    PWRITE(0, 16384);
    asm volatile("s_waitcnt lgkmcnt(0)" ::: "memory");
    if (KT > 1) PLOAD(BbF, tile_n, 64);
  }

  for (int tt = 0; tt < KT; ++tt) {
    const int c = tt & 1;
    asm volatile("s_waitcnt vmcnt(0)" ::: "memory");
    __builtin_amdgcn_s_barrier();                      // buf c fully published
    if (tt + 1 < KT) {
      const int k0n = (tt + 1) << 6;
      if constexpr (PF32 == 1) {
        PWRITE(c ^ 1, 0);
        STAGE_FB(c ^ 1, k0n);
        if (tt + 2 < KT) PLOAD(AbF, tile_m, (tt + 2) << 6);
      } else if constexpr (PF32 == 2) {
        PWRITE(c ^ 1, 16384);
        STAGE_FA(c ^ 1, k0n);
        if (tt + 2 < KT) PLOAD(BbF, tile_n, (tt + 2) << 6);
      } else {
        STAGE_FA(c ^ 1, k0n); STAGE_FB(c ^ 1, k0n);
      }
    }
    if constexpr (PF32 == 0) {
      lx2 aA[4], bB[4];
#pragma unroll
      for (int mi = 0; mi < 4; ++mi)
        aA[mi] = *(const lx2*)(lds + c * 32768 + (wr * 4 + mi) * 1024 + lane * 16);
#pragma unroll
      for (int nf = 0; nf < 4; ++nf)
        bB[nf] = *(const lx2*)(lds + c * 32768 + 16384 + (wc * 4 + nf) * 1024 + lane * 16);
      asm volatile("s_waitcnt lgkmcnt(0)" ::: "memory");
      __builtin_amdgcn_sched_barrier(0);
      __builtin_amdgcn_s_setprio(1);
#pragma unroll
      for (int kk = 0; kk < 2; ++kk)
#pragma unroll
        for (int mi = 0; mi < 4; ++mi)
#pragma unroll
          for (int nf = 0; nf < 4; ++nf)
            acc[mi][nf] = __builtin_amdgcn_mfma_f32_16x16x32_fp8_fp8(
                aA[mi][kk], bB[nf][kk], acc[mi][nf], 0, 0, 0);
      __builtin_amdgcn_s_setprio(0);
    } else {
      // split A-frag reads (halves reg pressure): bB[4] + aAh[2]
      lx2 aAh[2], bB[4];
#pragma unroll
      for (int nf = 0; nf < 4; ++nf)
        bB[nf] = *(const lx2*)(lds + c * 32768 + 16384 + (wc * 4 + nf) * 1024 + lane * 16);
#pragma unroll
      for (int i = 0; i < 2; ++i)
        aAh[i] = *(const lx2*)(lds + c * 32768 + (wr * 4 + i) * 1024 + lane * 16);
      asm volatile("s_waitcnt lgkmcnt(0)" ::: "memory");   // also drains my PWRITE
      __builtin_amdgcn_sched_barrier(0);
      __builtin_amdgcn_s_setprio(1);
#pragma unroll
      for (int kk = 0; kk < 2; ++kk)
#pragma unroll
        for (int mi = 0; mi < 2; ++mi)
#pragma unroll
          for (int nf = 0; nf < 4; ++nf)
            acc[mi][nf] = __builtin_amdgcn_mfma_f32_16x16x32_fp8_fp8(
                aAh[mi][kk], bB[nf][kk], acc[mi][nf], 0, 0, 0);
      __builtin_amdgcn_s_setprio(0);
#pragma unroll
      for (int i = 0; i < 2; ++i)
        aAh[i] = *(const lx2*)(lds + c * 32768 + (wr * 4 + 2 + i) * 1024 + lane * 16);
      asm volatile("s_waitcnt lgkmcnt(0)" ::: "memory");
      __builtin_amdgcn_sched_barrier(0);
      __builtin_amdgcn_s_setprio(1);
#pragma unroll
      for (int kk = 0; kk < 2; ++kk)
#pragma unroll
        for (int mi = 0; mi < 2; ++mi)
#pragma unroll
          for (int nf = 0; nf < 4; ++nf)
            acc[2 + mi][nf] = __builtin_amdgcn_mfma_f32_16x16x32_fp8_fp8(
                aAh[mi][kk], bB[nf][kk], acc[2 + mi][nf], 0, 0, 0);
      __builtin_amdgcn_s_setprio(0);
    }
  }
#undef STAGE_FA
#undef STAGE_FB
#undef PLOAD
#undef PWRITE

  // ---- epilogue: 2 half-passes (128 rows) via LDS bf16, swizzled ----
  float sm2[4] = {0.f, 0.f, 0.f, 0.f};
  const int g5 = ((lane >> 4) & 3) << 5;
  int ccl[4]; float bcn[4];
#pragma unroll
  for (int nf = 0; nf < 4; ++nf) {
    ccl[nf] = wc * 64 + nf * 16 + (lane & 15);
    bcn[nf] = (BIAS_MODE == 1) ? bias[tile_n + ccl[nf]] : 0.f;
  }
#pragma unroll
  for (int h = 0; h < 2; ++h) {
    __syncthreads();
    if ((wr >> 1) == h) {
#pragma unroll
      for (int mi = 0; mi < 4; ++mi) {
#pragma unroll
        for (int j = 0; j < 4; ++j) {
          const int row = (wr & 1) * 64 + mi * 16 + ((lane >> 4) << 2) + j;  // 0..127
          float bcr = (BIAS_MODE == 2) ? bias[tile_m + h * 128 + row] : 0.f;
#pragma unroll
          for (int nf = 0; nf < 4; ++nf) {
            float val = acc[mi][nf][j];
            if (SCALED) val *= scale;
            if (BIAS_MODE == 1) val += bcn[nf];
            else if (BIAS_MODE == 2) val += bcr;
            if (EXPOUT) val = __expf(val);
            if (REDUCE == 2) sm2[nf] += val;
            *(ushort*)(lds + row * 512 + ((ccl[nf] * 2) ^ g5)) = f2bf(val);
          }
        }
      }
    }
    __syncthreads();
    // coalesced flush: 4 passes x 1024 thr x 16B LDS
#pragma unroll
    for (int p = 0; p < 4; ++p) {
      int off = p * 16384 + t * 16;
      int row = off >> 9;
      int b = off & 511;
      int bs = b ^ (((row >> 2) & 3) << 5);
      f32x4 d = *(const f32x4*)(lds + row * 512 + bs);
      const int gr = tile_m + h * 128 + row;
      if (OUT_FP8) {
        const uint* dw = (const uint*)&d;
        float f0 = bf2f((ushort)(dw[0] & 0xffff)), f1 = bf2f((ushort)(dw[0] >> 16));
        float f2 = bf2f((ushort)(dw[1] & 0xffff)), f3 = bf2f((ushort)(dw[1] >> 16));
        float f4 = bf2f((ushort)(dw[2] & 0xffff)), f5 = bf2f((ushort)(dw[2] >> 16));
        float f6 = bf2f((ushort)(dw[3] & 0xffff)), f7 = bf2f((ushort)(dw[3] >> 16));
        uint2 o;
        o.x = pk4_fp8(f0, f1, f2, f3);
        o.y = pk4_fp8(f4, f5, f6, f7);
        *(uint2*)((unsigned char*)Cv + (size_t)bz * sC + (size_t)gr * N + tile_n + (b >> 1)) = o;
      } else {
        *(f32x4*)((ushort*)Cv + (size_t)bz * sC + (size_t)gr * N + tile_n + (b >> 1)) = d;
      }
    }
  }

  if constexpr (REDUCE == 2) {
    __syncthreads();
    float* sb = (float*)lds;   // [4][256]
#pragma unroll
    for (int nf = 0; nf < 4; ++nf) {
      float s1 = sm2[nf] + __shfl_xor(sm2[nf], 16);
      float Ss = s1 + __shfl_xor(s1, 32);
      if ((lane >> 4) == nf) sb[wr * 256 + ccl[nf]] = Ss;
    }
    __syncthreads();
    if (t < 256) {
      size_t rb = ((size_t)bz * gm + (tile_m >> 8)) * N + tile_n + t;
      red_sum[rb] = sb[t] + sb[256 + t] + sb[512 + t] + sb[768 + t];
    }
  }
  if constexpr (REDUCE == 1) {
    __syncthreads();
    float* mb = (float*)lds;          // [4][256]
    float* sb = (float*)lds + 1024;   // [4][256]
#pragma unroll
    for (int nf = 0; nf < 4; ++nf) {
      float mx = -1e30f;
#pragma unroll
      for (int mi = 0; mi < 4; ++mi)
#pragma unroll
        for (int j = 0; j < 4; ++j) {
          float val = acc[mi][nf][j];
          if (SCALED) val *= scale;
          mx = fmaxf(mx, val);
        }
      float m1 = fmaxf(mx, __shfl_xor(mx, 16));
      float M = fmaxf(m1, __shfl_xor(m1, 32));
      float sm = 0.f;
#pragma unroll
      for (int mi = 0; mi < 4; ++mi)
#pragma unroll
        for (int j = 0; j < 4; ++j) {
          float val = acc[mi][nf][j];
          if (SCALED) val *= scale;
          sm += __expf(val - M);
        }
      float s1 = sm + __shfl_xor(sm, 16);
      float Ss = s1 + __shfl_xor(s1, 32);
      if ((lane >> 4) == nf) {
        mb[wr * 256 + ccl[nf]] = M;
        sb[wr * 256 + ccl[nf]] = Ss;
      }
    }
    __syncthreads();
    if (t < 256) {
      float M = fmaxf(fmaxf(mb[t], mb[256 + t]), fmaxf(mb[512 + t], mb[768 + t]));
      float Ss = sb[t] * __expf(mb[t] - M) + sb[256 + t] * __expf(mb[256 + t] - M) +
                 sb[512 + t] * __expf(mb[512 + t] - M) + sb[768 + t] * __expf(mb[768 + t] - M);
      size_t rb = ((size_t)bz * gm + (tile_m >> 8)) * N + tile_n + t;
      red_max[rb] = M;
      red_sum[rb] = Ss;
    }
  }
}

// c[b,k] = 1024 / sum_ch red_sum[b][ch][k]   (x1024 keeps vs in fp8 range)
__global__ __launch_bounds__(256) void combine_c(
    const float* __restrict__ red_sum, float* __restrict__ cvec, int cols, int nch)
{
  const int b = blockIdx.y;
  const int c = blockIdx.x * 256 + threadIdx.x;
  float Z = 0.f;
  for (int ch = 0; ch < nch; ++ch)
    Z += red_sum[((size_t)b * nch + ch) * cols + c];
  cvec[(size_t)b * cols + c] = 1024.f / Z;
}

// vs[b][d][k] = fp8( vpT_fp8[b][d][k] * c[b][k] )   (8 elems/thread)
__global__ __launch_bounds__(256) void scale_v(
    const uint2* __restrict__ vpT, const float* __restrict__ cvec,
    uint2* __restrict__ vs, int S, long DS)
{
  const size_t i8 = (size_t)blockIdx.x * 256 + threadIdx.x;
  const size_t k8 = i8 * 8;
  const int b = (int)(k8 / DS);
  const int kcol = (int)(k8 % S);
  uint2 u = vpT[i8];
  const float* cb = cvec + (size_t)b * S + kcol;
  float f0 = FP8DEC(u.x, 0) * cb[0], f1 = FP8DEC(u.x, 1) * cb[1];
  float f2 = FP8DEC(u.x, 2) * cb[2], f3 = FP8DEC(u.x, 3) * cb[3];
  float f4 = FP8DEC(u.y, 0) * cb[4], f5 = FP8DEC(u.y, 1) * cb[5];
  float f6 = FP8DEC(u.y, 2) * cb[6], f7 = FP8DEC(u.y, 3) * cb[7];
  uint2 o;
  o.x = pk4_fp8(f0, f1, f2, f3);
  o.y = pk4_fp8(f4, f5, f6, f7);
  vs[i8] = o;
}

// combine partials -> M, 1/Z per (b,col). grid: (cols/256, B)
__global__ __launch_bounds__(256) void colsm_combine(
    const float* __restrict__ red_max, const float* __restrict__ red_sum,
    float* __restrict__ Mv, float* __restrict__ Zinv, int cols, int nch)
{
  const int b = blockIdx.y;
  const int c = blockIdx.x * 256 + threadIdx.x;
  float M = -1e30f, Z = 0.f;
  for (int ch = 0; ch < nch; ++ch) {
    size_t o = ((size_t)b * nch + ch) * cols + c;
    float m = red_max[o], s = red_sum[o];
    float nm = fmaxf(M, m);
    Z = Z * __expf(M - nm) + s * __expf(m - nm);
    M = nm;
  }
  Mv[(size_t)b * cols + c] = M;
  Zinv[(size_t)b * cols + c] = 1.f / Z;
}

// final: out1 = softmax(attn over rows), out0 = attn + residual. attn is bf16.
__global__ __launch_bounds__(256) void final_emit(
    const ushort* __restrict__ attnB, const float* __restrict__ q,
    float* __restrict__ out0, float* __restrict__ out1,
    const float* __restrict__ Mv, const float* __restrict__ Zinv,
    int rows, int cols, int rpc)
{
  const int b = blockIdx.y;
  const int ch = blockIdx.z;
  const size_t base = (size_t)b * rows * cols;
  const int c4 = (blockIdx.x * 256 + threadIdx.x) * 4;
  const int r0 = ch * rpc;
  float M[4], Zi[4];
#pragma unroll
  for (int i = 0; i < 4; ++i) {
    M[i] = Mv[(size_t)b * cols + c4 + i];
    Zi[i] = Zinv[(size_t)b * cols + c4 + i];
  }
  for (int r = r0; r < r0 + rpc; ++r) {
    size_t o = base + (size_t)r * cols + c4;
    ushort4 u = *(const ushort4*)(attnB + o);
    float4 qv = *(const float4*)(q + o);
    float a0 = bf2f(u.x), a1 = bf2f(u.y), a2 = bf2f(u.z), a3 = bf2f(u.w);
    float4 wv, s;
    wv.x = __expf(a0 - M[0]) * Zi[0];
    wv.y = __expf(a1 - M[1]) * Zi[1];
    wv.z = __expf(a2 - M[2]) * Zi[2];
    wv.w = __expf(a3 - M[3]) * Zi[3];
    s.x = a0 + qv.x; s.y = a1 + qv.y; s.z = a2 + qv.z; s.w = a3 + qv.w;
    *(float4*)(out1 + o) = wv;
    *(float4*)(out0 + o) = s;
  }
}

extern "C" void kernel_launch(void* const* d_in, const int* in_sizes, int n_in,
                              void* d_out, int out_size, void* d_ws, size_t ws_size,
                              hipStream_t stream) {
  const float* q  = (const float*)d_in[0];
  const float* k  = (const float*)d_in[1];
  const float* v  = (const float*)d_in[2];
  const float* Wq = (const float*)d_in[3];
  const float* bq = (const float*)d_in[4];
  const float* Wk = (const float*)d_in[5];
  const float* bk = (const float*)d_in[6];
  const float* Wv = (const float*)d_in[7];
  const float* bv = (const float*)d_in[8];
  float* out = (float*)d_out;

  const int B = 8, S = 2048, D = 1024;
  const long BS = (long)B * S;
  const long nQKV = BS * D;
  const long nW = (long)D * D;

  // d_out: Wq8/Wk8/Wv8 fp8 @0/1/2MB; red_s_sum @64M; c_s @66M.
  // final_emit overwrites all of d_out at the end.
  unsigned char* Wq8 = (unsigned char*)d_out;
  unsigned char* Wk8 = Wq8 + nW;
  unsigned char* Wv8 = Wk8 + nW;
  float* red_s_sum = (float*)((char*)d_out + (64ull << 20));
  float* c_s       = (float*)((char*)d_out + (66ull << 20));

  // ws: qp8 [0,16M), kp8 [16,32M), vpT8 [32,48M), vs8 [48,64M),
  //     expS8 [64,96M), attnB bf16 [96,128M), red_f/Mf/Zf @128M+.
  char* ws = (char*)d_ws;
  unsigned char* qp8   = (unsigned char*)ws;
  unsigned char* kp8   = (unsigned char*)(ws + (16ull << 20));
  unsigned char* vpT8  = (unsigned char*)(ws + (32ull << 20));
  unsigned char* vs8   = (unsigned char*)(ws + (48ull << 20));
  unsigned char* expS8 = (unsigned char*)(ws + (64ull << 20));
  ushort* attnB        = (ushort*)(ws + (96ull << 20));
  float* red_f_max = (float*)(ws + (128ull << 20));
  float* red_f_sum = (float*)(ws + (129ull << 20));
  float* Mf        = (float*)(ws + (130ull << 20));
  float* Zf        = (float*)(ws + (131ull << 20));

  const int SH = 65536;
  (void)hipFuncSetAttribute(reinterpret_cast<const void*>(&gemmF<1,0,0,0,1,1>),
                            hipFuncAttributeMaxDynamicSharedMemorySize, SH);
  (void)hipFuncSetAttribute(reinterpret_cast<const void*>(&gemmF<2,0,0,0,1,2>),
                            hipFuncAttributeMaxDynamicSharedMemorySize, SH);
  (void)hipFuncSetAttribute(reinterpret_cast<const void*>(&gemmF<0,1,2,1,1,0>),
                            hipFuncAttributeMaxDynamicSharedMemorySize, SH);
  (void)hipFuncSetAttribute(reinterpret_cast<const void*>(&gemmF<0,1,1,0,0,0>),
                            hipFuncAttributeMaxDynamicSharedMemorySize, SH);

  // ---- fp32 -> fp8 conversion: weights only (12 MB read) ----
  cvt3_fp8<<<dim3((unsigned)(nW / 4096), 3), 256, 0, stream>>>(
      Wq, Wk, Wv, (uint*)Wq8, (uint*)Wk8, (uint*)Wv8, nW);

  // qp[m][e] = q·Wq + bq (fp8 out); A = q fp32 reg-staged (fused cvt)
  gemmF<1,0,0,0,1,1><<<dim3(64 * 4), 1024, SH, stream>>>(
      q, Wq8, qp8, bq, nullptr, nullptr, D, D, 0, 0, 0, 1.f, 64, 4);
  gemmF<1,0,0,0,1,1><<<dim3(64 * 4), 1024, SH, stream>>>(
      k, Wk8, kp8, bk, nullptr, nullptr, D, D, 0, 0, 0, 1.f, 64, 4);
  // vpT[b][e][s] = Wv·v^T + bv (row bias, fp8 out); B = v fp32 reg-staged
  gemmF<2,0,0,0,1,2><<<dim3(4 * 8 * B), 1024, SH, stream>>>(
      Wv8, v, vpT8, bv, nullptr, nullptr, S, D, 0, (long)S * D, (long)D * S, 1.f, 4, 8);
  // expS = exp(qp·kp^T / 1024) (fp8 out) + fused col-sum partials
  gemmF<0,1,2,1,1,0><<<dim3(8 * 8 * B), 1024, SH, stream>>>(
      qp8, kp8, expS8, nullptr, nullptr, red_s_sum,
      S, D, (long)S * D, (long)S * D, (long)S * S, 1.f / 1024.f, 8, 8);

  // c = 1024/colsum;  vs = vpT * c  (fp8)
  combine_c<<<dim3(S / 256, B), 256, 0, stream>>>(red_s_sum, c_s, S, 8);
  scale_v<<<dim3((int)(nQKV / (256 * 8))), 256, 0, stream>>>(
      (const uint2*)vpT8, c_s, (uint2*)vs8, S, (long)D * S);

  // attn = (expS·vs^T)/1024 (bf16 out) + fused final-softmax pass1
  gemmF<0,1,1,0,0,0><<<dim3(8 * 4 * B), 1024, SH, stream>>>(
      expS8, vs8, attnB, nullptr, red_f_max, red_f_sum,
      D, S, (long)S * S, (long)D * S, (long)S * D, 1.f / 1024.f, 8, 4);

  colsm_combine<<<dim3(D / 256, B), 256, 0, stream>>>(red_f_max, red_f_sum, Mf, Zf, D, 8);
  final_emit<<<dim3(1, B, 128), 256, 0, stream>>>(attnB, q, out, out + nQKV, Mf, Zf, S, D, 16);

  (void)in_sizes; (void)n_in; (void)out_size; (void)ws_size;
}

// Round 20
// 313.609 us; speedup vs baseline: 1.1141x; 1.0905x over previous
//
#include <hip/hip_runtime.h>

typedef __attribute__((ext_vector_type(2))) long lx2;
typedef __attribute__((ext_vector_type(4))) float f32x4;

__device__ __forceinline__ ushort f2bf(float f) {
  union { float f; unsigned u; } x; x.f = f;
  unsigned r = x.u + 0x7FFFu + ((x.u >> 16) & 1u);
  return (ushort)(r >> 16);
}
__device__ __forceinline__ float bf2f(ushort u) {
  union { unsigned u; float f; } x; x.u = ((unsigned)u) << 16;
  return x.f;
}

// ---------------- fp8 e4m3 encode/decode ----------------
#if defined(__has_builtin)
#if __has_builtin(__builtin_amdgcn_cvt_pk_fp8_f32) && __has_builtin(__builtin_amdgcn_cvt_f32_fp8)
#define HAVE_HW_FP8 1
#endif
#endif

#ifdef HAVE_HW_FP8
__device__ __forceinline__ uint pk4_fp8(float f0, float f1, float f2, float f3) {
  int r = __builtin_amdgcn_cvt_pk_fp8_f32(f0, f1, 0, false);
  r = __builtin_amdgcn_cvt_pk_fp8_f32(f2, f3, r, true);
  return (uint)r;
}
#define FP8DEC(dw, sel) __builtin_amdgcn_cvt_f32_fp8((int)(dw), (sel))
#else
// software OCP e4m3fn: value = (8+M)*2^(E-10) for E>=1; M*2^-9 subnormal; max 448.
__device__ __forceinline__ unsigned char f2e4m3(float f) {
  unsigned u = __float_as_uint(f);
  unsigned s = (u >> 24) & 0x80;
  float a = fabsf(f);
  if (a != a) return (unsigned char)(s | 0x7f);
  if (a >= 448.f) return (unsigned char)(s | 0x7e);
  int ei;
  (void)frexpf(a, &ei);
  int E = ei + 6;
  if (E < 1) {
    int ki = (int)rintf(a * 512.f);
    if (ki >= 8) return (unsigned char)(s | 0x08);
    return (unsigned char)(s | ki);
  }
  float q = a * exp2f((float)(10 - E));
  int ki = (int)rintf(q);
  if (ki >= 16) { E++; ki = 8; }
  if (E > 15 || (E == 15 && ki > 14)) return (unsigned char)(s | 0x7e);
  return (unsigned char)(s | (E << 3) | (ki - 8));
}
__device__ __forceinline__ uint pk4_fp8(float f0, float f1, float f2, float f3) {
  return (uint)f2e4m3(f0) | ((uint)f2e4m3(f1) << 8) |
         ((uint)f2e4m3(f2) << 16) | ((uint)f2e4m3(f3) << 24);
}
__device__ __forceinline__ float e4m3dec(unsigned char b) {
  int E = (b >> 3) & 15, M = b & 7;
  float v = E ? ldexpf((float)(8 + M), E - 10) : ldexpf((float)M, -9);
  return (b & 0x80) ? -v : v;
}
#define FP8DEC(dw, sel) e4m3dec((unsigned char)(((dw) >> (8 * (sel))) & 0xff))
#endif

__device__ __forceinline__ void gload_lds16(const void* g, void* l) {
  __builtin_amdgcn_global_load_lds(
      (const __attribute__((address_space(1))) void*)g,
      (__attribute__((address_space(3))) void*)l, 16, 0, 0);
}

// ------- fp32 -> fp8, grid-stride software-pipelined (8 loads in flight) -------
// Thread handles 16 contiguous elems/iter (4x float4 load, 1x uint4 store);
// next iter's loads issued before converting current. grid: (blocks, 3).
__global__ __launch_bounds__(256) void cvt3_fp8(
    const float* __restrict__ s0, const float* __restrict__ s1,
    const float* __restrict__ s2, uint* __restrict__ d0,
    uint* __restrict__ d1, uint* __restrict__ d2, long n16) {
  const float4* s = (const float4*)(blockIdx.y == 0 ? s0 : (blockIdx.y == 1 ? s1 : s2));
  uint* d = blockIdx.y == 0 ? d0 : (blockIdx.y == 1 ? d1 : d2);
  long i = (long)blockIdx.x * 256 + threadIdx.x;
  const long stride = (long)gridDim.x * 256;
  if (i >= n16) return;
  float4 a0 = s[i * 4], a1 = s[i * 4 + 1], a2 = s[i * 4 + 2], a3 = s[i * 4 + 3];
  for (;;) {
    const long inext = i + stride;
    const bool more = inext < n16;
    float4 b0, b1, b2, b3;
    if (more) { b0 = s[inext * 4]; b1 = s[inext * 4 + 1];
                b2 = s[inext * 4 + 2]; b3 = s[inext * 4 + 3]; }
    uint4 o;
    o.x = pk4_fp8(a0.x, a0.y, a0.z, a0.w);
    o.y = pk4_fp8(a1.x, a1.y, a1.z, a1.w);
    o.z = pk4_fp8(a2.x, a2.y, a2.z, a2.w);
    o.w = pk4_fp8(a3.x, a3.y, a3.z, a3.w);
    *(uint4*)(d + i * 4) = o;
    if (!more) break;
    i = inext;
    a0 = b0; a1 = b1; a2 = b2; a3 = b3;
  }
}

// ============ 256x256 16-wave fp8 GEMM (B^T form), 1 barrier / K-tile ============
// (round-17 proven structure, verbatim)
template<int BIAS_MODE, int SCALED, int REDUCE, int EXPOUT, int OUT_FP8>
__global__ __launch_bounds__(1024, 4) void gemmF(
    const unsigned char* __restrict__ A, const unsigned char* __restrict__ B,
    void* __restrict__ Cv, const float* __restrict__ bias,
    float* __restrict__ red_max, float* __restrict__ red_sum,
    int N, int K, long sA, long sB, long sC, float scale, int gm, int gn)
{
  extern __shared__ unsigned char lds[];   // 65536 B

  // ---- tile decode: bijective XCD swizzle + banded order ----
  const int nwg = gridDim.x;
  const int wg = blockIdx.x;
  const int cpx = nwg >> 3;
  const int wid_ = (wg & 7) * cpx + (wg >> 3);
  const int tiles = gm * gn;
  const int bz = wid_ / tiles;
  const int t2 = wid_ - bz * tiles;
  const int band = t2 / (gm << 2);
  const int r2 = t2 - band * (gm << 2);
  const int tile_m = (r2 >> 2) * 256;
  const int tile_n = ((band << 2) + (r2 & 3)) * 256;

  const unsigned char* Ab = A + (size_t)bz * sA;
  const unsigned char* Bb = B + (size_t)bz * sB;
  const int t = threadIdx.x;
  const int lane = t & 63;
  const int w = t >> 6;        // 0..15
  const int wr = w >> 2;       // 0..3
  const int wc = w & 3;        // 0..3

  f32x4 acc[4][4] = {};

#define STAGE(c, k0)                                                                   \
  do {                                                                                 \
    gload_lds16(Ab + (size_t)(tile_m + w * 16 + (lane & 15)) * K + (k0) +              \
                    (lane >> 4) * 16,                                                  \
                lds + (c) * 32768 + w * 1024);                                         \
    gload_lds16(Bb + (size_t)(tile_n + w * 16 + (lane & 15)) * K + (k0) +              \
                    (lane >> 4) * 16,                                                  \
                lds + (c) * 32768 + 16384 + w * 1024);                                 \
  } while (0)

  // ---- prologue ----
  STAGE(0, 0);

  const int KT = K >> 6;
  for (int tt = 0; tt < KT; ++tt) {
    const int c = tt & 1;
    asm volatile("s_waitcnt vmcnt(0)" ::: "memory");   // tile tt's 2 stages (1-tile dist)
    __builtin_amdgcn_s_barrier();                      // publish all waves' stages
    if (tt + 1 < KT) STAGE(c ^ 1, (tt + 1) << 6);
    lx2 aA[4], bB[4];
#pragma unroll
    for (int mi = 0; mi < 4; ++mi)
      aA[mi] = *(const lx2*)(lds + c * 32768 + (wr * 4 + mi) * 1024 + lane * 16);
#pragma unroll
    for (int nf = 0; nf < 4; ++nf)
      bB[nf] = *(const lx2*)(lds + c * 32768 + 16384 + (wc * 4 + nf) * 1024 + lane * 16);
    asm volatile("s_waitcnt lgkmcnt(0)" ::: "memory");
    __builtin_amdgcn_sched_barrier(0);
    __builtin_amdgcn_s_setprio(1);
#pragma unroll
    for (int kk = 0; kk < 2; ++kk)
#pragma unroll
      for (int mi = 0; mi < 4; ++mi)
#pragma unroll
        for (int nf = 0; nf < 4; ++nf)
          acc[mi][nf] = __builtin_amdgcn_mfma_f32_16x16x32_fp8_fp8(
              aA[mi][kk], bB[nf][kk], acc[mi][nf], 0, 0, 0);
    __builtin_amdgcn_s_setprio(0);
  }
#undef STAGE

  // ---- epilogue: 2 half-passes (128 rows) via LDS bf16, swizzled ----
  float sm2[4] = {0.f, 0.f, 0.f, 0.f};
  const int g5 = ((lane >> 4) & 3) << 5;
  int ccl[4]; float bcn[4];
#pragma unroll
  for (int nf = 0; nf < 4; ++nf) {
    ccl[nf] = wc * 64 + nf * 16 + (lane & 15);
    bcn[nf] = (BIAS_MODE == 1) ? bias[tile_n + ccl[nf]] : 0.f;
  }
#pragma unroll
  for (int h = 0; h < 2; ++h) {
    __syncthreads();
    if ((wr >> 1) == h) {
#pragma unroll
      for (int mi = 0; mi < 4; ++mi) {
#pragma unroll
        for (int j = 0; j < 4; ++j) {
          const int row = (wr & 1) * 64 + mi * 16 + ((lane >> 4) << 2) + j;  // 0..127
          float bcr = (BIAS_MODE == 2) ? bias[tile_m + h * 128 + row] : 0.f;
#pragma unroll
          for (int nf = 0; nf < 4; ++nf) {
            float val = acc[mi][nf][j];
            if (SCALED) val *= scale;
            if (BIAS_MODE == 1) val += bcn[nf];
            else if (BIAS_MODE == 2) val += bcr;
            if (EXPOUT) val = __expf(val);
            if (REDUCE == 2) sm2[nf] += val;
            *(ushort*)(lds + row * 512 + ((ccl[nf] * 2) ^ g5)) = f2bf(val);
          }
        }
      }
    }
    __syncthreads();
    // coalesced flush: 4 passes x 1024 thr x 16B LDS
#pragma unroll
    for (int p = 0; p < 4; ++p) {
      int off = p * 16384 + t * 16;
      int row = off >> 9;
      int b = off & 511;
      int bs = b ^ (((row >> 2) & 3) << 5);
      f32x4 d = *(const f32x4*)(lds + row * 512 + bs);
      const int gr = tile_m + h * 128 + row;
      if (OUT_FP8) {
        const uint* dw = (const uint*)&d;
        float f0 = bf2f((ushort)(dw[0] & 0xffff)), f1 = bf2f((ushort)(dw[0] >> 16));
        float f2 = bf2f((ushort)(dw[1] & 0xffff)), f3 = bf2f((ushort)(dw[1] >> 16));
        float f4 = bf2f((ushort)(dw[2] & 0xffff)), f5 = bf2f((ushort)(dw[2] >> 16));
        float f6 = bf2f((ushort)(dw[3] & 0xffff)), f7 = bf2f((ushort)(dw[3] >> 16));
        uint2 o;
        o.x = pk4_fp8(f0, f1, f2, f3);
        o.y = pk4_fp8(f4, f5, f6, f7);
        *(uint2*)((unsigned char*)Cv + (size_t)bz * sC + (size_t)gr * N + tile_n + (b >> 1)) = o;
      } else {
        *(f32x4*)((ushort*)Cv + (size_t)bz * sC + (size_t)gr * N + tile_n + (b >> 1)) = d;
      }
    }
  }

  if constexpr (REDUCE == 2) {
    __syncthreads();
    float* sb = (float*)lds;   // [4][256]
#pragma unroll
    for (int nf = 0; nf < 4; ++nf) {
      float s1 = sm2[nf] + __shfl_xor(sm2[nf], 16);
      float Ss = s1 + __shfl_xor(s1, 32);
      if ((lane >> 4) == nf) sb[wr * 256 + ccl[nf]] = Ss;
    }
    __syncthreads();
    if (t < 256) {
      size_t rb = ((size_t)bz * gm + (tile_m >> 8)) * N + tile_n + t;
      red_sum[rb] = sb[t] + sb[256 + t] + sb[512 + t] + sb[768 + t];
    }
  }
  if constexpr (REDUCE == 1) {
    __syncthreads();
    float* mb = (float*)lds;          // [4][256]
    float* sb = (float*)lds + 1024;   // [4][256]
#pragma unroll
    for (int nf = 0; nf < 4; ++nf) {
      float mx = -1e30f;
#pragma unroll
      for (int mi = 0; mi < 4; ++mi)
#pragma unroll
        for (int j = 0; j < 4; ++j) {
          float val = acc[mi][nf][j];
          if (SCALED) val *= scale;
          mx = fmaxf(mx, val);
        }
      float m1 = fmaxf(mx, __shfl_xor(mx, 16));
      float M = fmaxf(m1, __shfl_xor(m1, 32));
      float sm = 0.f;
#pragma unroll
      for (int mi = 0; mi < 4; ++mi)
#pragma unroll
        for (int j = 0; j < 4; ++j) {
          float val = acc[mi][nf][j];
          if (SCALED) val *= scale;
          sm += __expf(val - M);
        }
      float s1 = sm + __shfl_xor(sm, 16);
      float Ss = s1 + __shfl_xor(s1, 32);
      if ((lane >> 4) == nf) {
        mb[wr * 256 + ccl[nf]] = M;
        sb[wr * 256 + ccl[nf]] = Ss;
      }
    }
    __syncthreads();
    if (t < 256) {
      float M = fmaxf(fmaxf(mb[t], mb[256 + t]), fmaxf(mb[512 + t], mb[768 + t]));
      float Ss = sb[t] * __expf(mb[t] - M) + sb[256 + t] * __expf(mb[256 + t] - M) +
                 sb[512 + t] * __expf(mb[512 + t] - M) + sb[768 + t] * __expf(mb[768 + t] - M);
      size_t rb = ((size_t)bz * gm + (tile_m >> 8)) * N + tile_n + t;
      red_max[rb] = M;
      red_sum[rb] = Ss;
    }
  }
}

// c[b,k] = 1024 / sum_ch red_sum[b][ch][k]   (x1024 keeps vs in fp8 range)
__global__ __launch_bounds__(256) void combine_c(
    const float* __restrict__ red_sum, float* __restrict__ cvec, int cols, int nch)
{
  const int b = blockIdx.y;
  const int c = blockIdx.x * 256 + threadIdx.x;
  float Z = 0.f;
  for (int ch = 0; ch < nch; ++ch)
    Z += red_sum[((size_t)b * nch + ch) * cols + c];
  cvec[(size_t)b * cols + c] = 1024.f / Z;
}

// vs[b][d][k] = fp8( vpT_fp8[b][d][k] * c[b][k] )   (8 elems/thread)
__global__ __launch_bounds__(256) void scale_v(
    const uint2* __restrict__ vpT, const float* __restrict__ cvec,
    uint2* __restrict__ vs, int S, long DS)
{
  const size_t i8 = (size_t)blockIdx.x * 256 + threadIdx.x;
  const size_t k8 = i8 * 8;
  const int b = (int)(k8 / DS);
  const int kcol = (int)(k8 % S);
  uint2 u = vpT[i8];
  const float* cb = cvec + (size_t)b * S + kcol;
  float f0 = FP8DEC(u.x, 0) * cb[0], f1 = FP8DEC(u.x, 1) * cb[1];
  float f2 = FP8DEC(u.x, 2) * cb[2], f3 = FP8DEC(u.x, 3) * cb[3];
  float f4 = FP8DEC(u.y, 0) * cb[4], f5 = FP8DEC(u.y, 1) * cb[5];
  float f6 = FP8DEC(u.y, 2) * cb[6], f7 = FP8DEC(u.y, 3) * cb[7];
  uint2 o;
  o.x = pk4_fp8(f0, f1, f2, f3);
  o.y = pk4_fp8(f4, f5, f6, f7);
  vs[i8] = o;
}

// combine partials -> M, 1/Z per (b,col). grid: (cols/256, B)
__global__ __launch_bounds__(256) void colsm_combine(
    const float* __restrict__ red_max, const float* __restrict__ red_sum,
    float* __restrict__ Mv, float* __restrict__ Zinv, int cols, int nch)
{
  const int b = blockIdx.y;
  const int c = blockIdx.x * 256 + threadIdx.x;
  float M = -1e30f, Z = 0.f;
  for (int ch = 0; ch < nch; ++ch) {
    size_t o = ((size_t)b * nch + ch) * cols + c;
    float m = red_max[o], s = red_sum[o];
    float nm = fmaxf(M, m);
    Z = Z * __expf(M - nm) + s * __expf(m - nm);
    M = nm;
  }
  Mv[(size_t)b * cols + c] = M;
  Zinv[(size_t)b * cols + c] = 1.f / Z;
}

// final: out1 = softmax(attn over rows), out0 = attn + residual. attn is bf16.
__global__ __launch_bounds__(256) void final_emit(
    const ushort* __restrict__ attnB, const float* __restrict__ q,
    float* __restrict__ out0, float* __restrict__ out1,
    const float* __restrict__ Mv, const float* __restrict__ Zinv,
    int rows, int cols, int rpc)
{
  const int b = blockIdx.y;
  const int ch = blockIdx.z;
  const size_t base = (size_t)b * rows * cols;
  const int c4 = (blockIdx.x * 256 + threadIdx.x) * 4;
  const int r0 = ch * rpc;
  float M[4], Zi[4];
#pragma unroll
  for (int i = 0; i < 4; ++i) {
    M[i] = Mv[(size_t)b * cols + c4 + i];
    Zi[i] = Zinv[(size_t)b * cols + c4 + i];
  }
  for (int r = r0; r < r0 + rpc; ++r) {
    size_t o = base + (size_t)r * cols + c4;
    ushort4 u = *(const ushort4*)(attnB + o);
    float4 qv = *(const float4*)(q + o);
    float a0 = bf2f(u.x), a1 = bf2f(u.y), a2 = bf2f(u.z), a3 = bf2f(u.w);
    float4 wv, s;
    wv.x = __expf(a0 - M[0]) * Zi[0];
    wv.y = __expf(a1 - M[1]) * Zi[1];
    wv.z = __expf(a2 - M[2]) * Zi[2];
    wv.w = __expf(a3 - M[3]) * Zi[3];
    s.x = a0 + qv.x; s.y = a1 + qv.y; s.z = a2 + qv.z; s.w = a3 + qv.w;
    *(float4*)(out1 + o) = wv;
    *(float4*)(out0 + o) = s;
  }
}

extern "C" void kernel_launch(void* const* d_in, const int* in_sizes, int n_in,
                              void* d_out, int out_size, void* d_ws, size_t ws_size,
                              hipStream_t stream) {
  const float* q  = (const float*)d_in[0];
  const float* k  = (const float*)d_in[1];
  const float* v  = (const float*)d_in[2];
  const float* Wq = (const float*)d_in[3];
  const float* bq = (const float*)d_in[4];
  const float* Wk = (const float*)d_in[5];
  const float* bk = (const float*)d_in[6];
  const float* Wv = (const float*)d_in[7];
  const float* bv = (const float*)d_in[8];
  float* out = (float*)d_out;

  const int B = 8, S = 2048, D = 1024;
  const long BS = (long)B * S;
  const long nQKV = BS * D;        // 16.7M elems
  const long nW = (long)D * D;

  // d_out staging (fp8): qb [0,16M), kb [16,32M), vb [32,48M),
  // Wq8/Wk8/Wv8 @48/49/50M; red_s_sum @64M (512KB); c_s @66M (64KB).
  // final_emit overwrites all of d_out at the end.
  unsigned char* qb8 = (unsigned char*)d_out;
  unsigned char* kb8 = qb8 + nQKV;
  unsigned char* vb8 = kb8 + nQKV;
  unsigned char* Wq8 = (unsigned char*)d_out + (48ull << 20);
  unsigned char* Wk8 = (unsigned char*)d_out + (49ull << 20);
  unsigned char* Wv8 = (unsigned char*)d_out + (50ull << 20);
  float* red_s_sum = (float*)((char*)d_out + (64ull << 20));
  float* c_s       = (float*)((char*)d_out + (66ull << 20));

  // ws: qp8 [0,16M), kp8 [16,32M), vpT8 [32,48M), vs8 [48,64M),
  //     expS8 [64,96M), attnB bf16 [96,128M), red_f/Mf/Zf @128M+.
  char* ws = (char*)d_ws;
  unsigned char* qp8   = (unsigned char*)ws;
  unsigned char* kp8   = (unsigned char*)(ws + (16ull << 20));
  unsigned char* vpT8  = (unsigned char*)(ws + (32ull << 20));
  unsigned char* vs8   = (unsigned char*)(ws + (48ull << 20));
  unsigned char* expS8 = (unsigned char*)(ws + (64ull << 20));
  ushort* attnB        = (ushort*)(ws + (96ull << 20));
  float* red_f_max = (float*)(ws + (128ull << 20));
  float* red_f_sum = (float*)(ws + (129ull << 20));
  float* Mf        = (float*)(ws + (130ull << 20));
  float* Zf        = (float*)(ws + (131ull << 20));

  const int SH = 65536;
  (void)hipFuncSetAttribute(reinterpret_cast<const void*>(&gemmF<1,0,0,0,1>),
                            hipFuncAttributeMaxDynamicSharedMemorySize, SH);
  (void)hipFuncSetAttribute(reinterpret_cast<const void*>(&gemmF<2,0,0,0,1>),
                            hipFuncAttributeMaxDynamicSharedMemorySize, SH);
  (void)hipFuncSetAttribute(reinterpret_cast<const void*>(&gemmF<0,1,2,1,1>),
                            hipFuncAttributeMaxDynamicSharedMemorySize, SH);
  (void)hipFuncSetAttribute(reinterpret_cast<const void*>(&gemmF<0,1,1,0,0>),
                            hipFuncAttributeMaxDynamicSharedMemorySize, SH);

  // ---- fp32 -> fp8 conversions: 2 launches (weights; q/k/v), grid-stride ----
  cvt3_fp8<<<dim3(256, 3), 256, 0, stream>>>(
      Wq, Wk, Wv, (uint*)Wq8, (uint*)Wk8, (uint*)Wv8, nW / 16);
  cvt3_fp8<<<dim3(2048, 3), 256, 0, stream>>>(
      q, k, v, (uint*)qb8, (uint*)kb8, (uint*)vb8, nQKV / 16);

  // qp[m][e] = q·Wq + bq (fp8 out)   gm=64, gn=4 -> 256 blocks
  gemmF<1,0,0,0,1><<<dim3(64 * 4), 1024, SH, stream>>>(
      qb8, Wq8, qp8, bq, nullptr, nullptr, D, D, 0, 0, 0, 1.f, 64, 4);
  gemmF<1,0,0,0,1><<<dim3(64 * 4), 1024, SH, stream>>>(
      kb8, Wk8, kp8, bk, nullptr, nullptr, D, D, 0, 0, 0, 1.f, 64, 4);
  // vpT[b][e][s] = Wv·v^T + bv (row bias, fp8 out)   gm=4, gn=8, batch 8
  gemmF<2,0,0,0,1><<<dim3(4 * 8 * B), 1024, SH, stream>>>(
      Wv8, vb8, vpT8, bv, nullptr, nullptr, S, D, 0, (long)S * D, (long)D * S, 1.f, 4, 8);
  // expS = exp(qp·kp^T / 1024) (fp8 out) + fused col-sum partials   gm=8, gn=8, b8
  gemmF<0,1,2,1,1><<<dim3(8 * 8 * B), 1024, SH, stream>>>(
      qp8, kp8, expS8, nullptr, nullptr, red_s_sum,
      S, D, (long)S * D, (long)S * D, (long)S * S, 1.f / 1024.f, 8, 8);

  // c = 1024/colsum;  vs = vpT * c  (fp8)
  combine_c<<<dim3(S / 256, B), 256, 0, stream>>>(red_s_sum, c_s, S, 8);
  scale_v<<<dim3((int)(nQKV / (256 * 8))), 256, 0, stream>>>(
      (const uint2*)vpT8, c_s, (uint2*)vs8, S, (long)D * S);

  // attn = (expS·vs^T)/1024 (bf16 out) + fused final-softmax pass1  gm=8, gn=4, b8
  gemmF<0,1,1,0,0><<<dim3(8 * 4 * B), 1024, SH, stream>>>(
      expS8, vs8, attnB, nullptr, red_f_max, red_f_sum,
      D, S, (long)S * S, (long)D * S, (long)S * D, 1.f / 1024.f, 8, 4);

  colsm_combine<<<dim3(D / 256, B), 256, 0, stream>>>(red_f_max, red_f_sum, Mf, Zf, D, 8);
  final_emit<<<dim3(1, B, 128), 256, 0, stream>>>(attnB, q, out, out + nQKV, Mf, Zf, S, D, 16);

  (void)in_sizes; (void)n_in; (void)out_size; (void)ws_size;
}

// Round 21
// 305.366 us; speedup vs baseline: 1.1442x; 1.0270x over previous
//
#include <hip/hip_runtime.h>

typedef __attribute__((ext_vector_type(2))) long lx2;
typedef __attribute__((ext_vector_type(4))) float f32x4;

__device__ __forceinline__ ushort f2bf(float f) {
  union { float f; unsigned u; } x; x.f = f;
  unsigned r = x.u + 0x7FFFu + ((x.u >> 16) & 1u);
  return (ushort)(r >> 16);
}
__device__ __forceinline__ float bf2f(ushort u) {
  union { unsigned u; float f; } x; x.u = ((unsigned)u) << 16;
  return x.f;
}

// ---------------- fp8 e4m3 encode ----------------
#if defined(__has_builtin)
#if __has_builtin(__builtin_amdgcn_cvt_pk_fp8_f32)
#define HAVE_HW_FP8 1
#endif
#endif

#ifdef HAVE_HW_FP8
__device__ __forceinline__ uint pk4_fp8(float f0, float f1, float f2, float f3) {
  int r = __builtin_amdgcn_cvt_pk_fp8_f32(f0, f1, 0, false);
  r = __builtin_amdgcn_cvt_pk_fp8_f32(f2, f3, r, true);
  return (uint)r;
}
#else
// software OCP e4m3fn: value = (8+M)*2^(E-10) for E>=1; M*2^-9 subnormal; max 448.
__device__ __forceinline__ unsigned char f2e4m3(float f) {
  unsigned u = __float_as_uint(f);
  unsigned s = (u >> 24) & 0x80;
  float a = fabsf(f);
  if (a != a) return (unsigned char)(s | 0x7f);
  if (a >= 448.f) return (unsigned char)(s | 0x7e);
  int ei;
  (void)frexpf(a, &ei);
  int E = ei + 6;
  if (E < 1) {
    int ki = (int)rintf(a * 512.f);
    if (ki >= 8) return (unsigned char)(s | 0x08);
    return (unsigned char)(s | ki);
  }
  float q = a * exp2f((float)(10 - E));
  int ki = (int)rintf(q);
  if (ki >= 16) { E++; ki = 8; }
  if (E > 15 || (E == 15 && ki > 14)) return (unsigned char)(s | 0x7e);
  return (unsigned char)(s | (E << 3) | (ki - 8));
}
__device__ __forceinline__ uint pk4_fp8(float f0, float f1, float f2, float f3) {
  return (uint)f2e4m3(f0) | ((uint)f2e4m3(f1) << 8) |
         ((uint)f2e4m3(f2) << 16) | ((uint)f2e4m3(f3) << 24);
}
#endif

__device__ __forceinline__ void gload_lds16(const void* g, void* l) {
  __builtin_amdgcn_global_load_lds(
      (const __attribute__((address_space(1))) void*)g,
      (__attribute__((address_space(3))) void*)l, 16, 0, 0);
}

// ------- fp32 -> fp8, grid-stride software-pipelined -------
__global__ __launch_bounds__(256) void cvt3_fp8(
    const float* __restrict__ s0, const float* __restrict__ s1,
    const float* __restrict__ s2, uint* __restrict__ d0,
    uint* __restrict__ d1, uint* __restrict__ d2, long n16) {
  const float4* s = (const float4*)(blockIdx.y == 0 ? s0 : (blockIdx.y == 1 ? s1 : s2));
  uint* d = blockIdx.y == 0 ? d0 : (blockIdx.y == 1 ? d1 : d2);
  long i = (long)blockIdx.x * 256 + threadIdx.x;
  const long stride = (long)gridDim.x * 256;
  if (i >= n16) return;
  float4 a0 = s[i * 4], a1 = s[i * 4 + 1], a2 = s[i * 4 + 2], a3 = s[i * 4 + 3];
  for (;;) {
    const long inext = i + stride;
    const bool more = inext < n16;
    float4 b0, b1, b2, b3;
    if (more) { b0 = s[inext * 4]; b1 = s[inext * 4 + 1];
                b2 = s[inext * 4 + 2]; b3 = s[inext * 4 + 3]; }
    uint4 o;
    o.x = pk4_fp8(a0.x, a0.y, a0.z, a0.w);
    o.y = pk4_fp8(a1.x, a1.y, a1.z, a1.w);
    o.z = pk4_fp8(a2.x, a2.y, a2.z, a2.w);
    o.w = pk4_fp8(a3.x, a3.y, a3.z, a3.w);
    *(uint4*)(d + i * 4) = o;
    if (!more) break;
    i = inext;
    a0 = b0; a1 = b1; a2 = b2; a3 = b3;
  }
}

// ============ 256x256 16-wave fp8 GEMM (B^T form), 1 barrier / K-tile ============
// C[m,n] = f((sum_k A[m,k]*B[n,k])*(SCALED?scale:1) + bias [* cscale_col]),
// f=exp if EXPOUT. CSCALE: epilogue multiplies by cscale[bz*N + col] (fused
// scale_v: vpT GEMM writes vs directly). Otherwise round-17 proven structure.
template<int BIAS_MODE, int SCALED, int REDUCE, int EXPOUT, int OUT_FP8, int CSCALE>
__global__ __launch_bounds__(1024, 4) void gemmF(
    const unsigned char* __restrict__ A, const unsigned char* __restrict__ B,
    void* __restrict__ Cv, const float* __restrict__ bias,
    const float* __restrict__ cscale,
    float* __restrict__ red_max, float* __restrict__ red_sum,
    int N, int K, long sA, long sB, long sC, float scale, int gm, int gn)
{
  extern __shared__ unsigned char lds[];   // 65536 B

  // ---- tile decode: bijective XCD swizzle + banded order ----
  const int nwg = gridDim.x;
  const int wg = blockIdx.x;
  const int cpx = nwg >> 3;
  const int wid_ = (wg & 7) * cpx + (wg >> 3);
  const int tiles = gm * gn;
  const int bz = wid_ / tiles;
  const int t2 = wid_ - bz * tiles;
  const int band = t2 / (gm << 2);
  const int r2 = t2 - band * (gm << 2);
  const int tile_m = (r2 >> 2) * 256;
  const int tile_n = ((band << 2) + (r2 & 3)) * 256;

  const unsigned char* Ab = A + (size_t)bz * sA;
  const unsigned char* Bb = B + (size_t)bz * sB;
  const int t = threadIdx.x;
  const int lane = t & 63;
  const int w = t >> 6;        // 0..15
  const int wr = w >> 2;       // 0..3
  const int wc = w & 3;        // 0..3

  f32x4 acc[4][4] = {};

#define STAGE(c, k0)                                                                   \
  do {                                                                                 \
    gload_lds16(Ab + (size_t)(tile_m + w * 16 + (lane & 15)) * K + (k0) +              \
                    (lane >> 4) * 16,                                                  \
                lds + (c) * 32768 + w * 1024);                                         \
    gload_lds16(Bb + (size_t)(tile_n + w * 16 + (lane & 15)) * K + (k0) +              \
                    (lane >> 4) * 16,                                                  \
                lds + (c) * 32768 + 16384 + w * 1024);                                 \
  } while (0)

  // ---- prologue ----
  STAGE(0, 0);

  const int KT = K >> 6;
  for (int tt = 0; tt < KT; ++tt) {
    const int c = tt & 1;
    asm volatile("s_waitcnt vmcnt(0)" ::: "memory");   // tile tt's 2 stages (1-tile dist)
    __builtin_amdgcn_s_barrier();                      // publish all waves' stages
    if (tt + 1 < KT) STAGE(c ^ 1, (tt + 1) << 6);
    lx2 aA[4], bB[4];
#pragma unroll
    for (int mi = 0; mi < 4; ++mi)
      aA[mi] = *(const lx2*)(lds + c * 32768 + (wr * 4 + mi) * 1024 + lane * 16);
#pragma unroll
    for (int nf = 0; nf < 4; ++nf)
      bB[nf] = *(const lx2*)(lds + c * 32768 + 16384 + (wc * 4 + nf) * 1024 + lane * 16);
    asm volatile("s_waitcnt lgkmcnt(0)" ::: "memory");
    __builtin_amdgcn_sched_barrier(0);
    __builtin_amdgcn_s_setprio(1);
#pragma unroll
    for (int kk = 0; kk < 2; ++kk)
#pragma unroll
      for (int mi = 0; mi < 4; ++mi)
#pragma unroll
        for (int nf = 0; nf < 4; ++nf)
          acc[mi][nf] = __builtin_amdgcn_mfma_f32_16x16x32_fp8_fp8(
              aA[mi][kk], bB[nf][kk], acc[mi][nf], 0, 0, 0);
    __builtin_amdgcn_s_setprio(0);
  }
#undef STAGE

  // ---- epilogue: 2 half-passes (128 rows) via LDS bf16, swizzled ----
  float sm2[4] = {0.f, 0.f, 0.f, 0.f};
  const int g5 = ((lane >> 4) & 3) << 5;
  int ccl[4]; float bcn[4]; float csc[4];
#pragma unroll
  for (int nf = 0; nf < 4; ++nf) {
    ccl[nf] = wc * 64 + nf * 16 + (lane & 15);
    bcn[nf] = (BIAS_MODE == 1) ? bias[tile_n + ccl[nf]] : 0.f;
    csc[nf] = (CSCALE) ? cscale[(size_t)bz * N + tile_n + ccl[nf]] : 1.f;
  }
#pragma unroll
  for (int h = 0; h < 2; ++h) {
    __syncthreads();
    if ((wr >> 1) == h) {
#pragma unroll
      for (int mi = 0; mi < 4; ++mi) {
#pragma unroll
        for (int j = 0; j < 4; ++j) {
          const int row = (wr & 1) * 64 + mi * 16 + ((lane >> 4) << 2) + j;  // 0..127
          float bcr = (BIAS_MODE == 2) ? bias[tile_m + h * 128 + row] : 0.f;
#pragma unroll
          for (int nf = 0; nf < 4; ++nf) {
            float val = acc[mi][nf][j];
            if (SCALED) val *= scale;
            if (BIAS_MODE == 1) val += bcn[nf];
            else if (BIAS_MODE == 2) val += bcr;
            if (CSCALE) val *= csc[nf];
            if (EXPOUT) val = __expf(val);
            if (REDUCE == 2) sm2[nf] += val;
            *(ushort*)(lds + row * 512 + ((ccl[nf] * 2) ^ g5)) = f2bf(val);
          }
        }
      }
    }
    __syncthreads();
    // coalesced flush: 4 passes x 1024 thr x 16B LDS
#pragma unroll
    for (int p = 0; p < 4; ++p) {
      int off = p * 16384 + t * 16;
      int row = off >> 9;
      int b = off & 511;
      int bs = b ^ (((row >> 2) & 3) << 5);
      f32x4 d = *(const f32x4*)(lds + row * 512 + bs);
      const int gr = tile_m + h * 128 + row;
      if (OUT_FP8) {
        const uint* dw = (const uint*)&d;
        float f0 = bf2f((ushort)(dw[0] & 0xffff)), f1 = bf2f((ushort)(dw[0] >> 16));
        float f2 = bf2f((ushort)(dw[1] & 0xffff)), f3 = bf2f((ushort)(dw[1] >> 16));
        float f4 = bf2f((ushort)(dw[2] & 0xffff)), f5 = bf2f((ushort)(dw[2] >> 16));
        float f6 = bf2f((ushort)(dw[3] & 0xffff)), f7 = bf2f((ushort)(dw[3] >> 16));
        uint2 o;
        o.x = pk4_fp8(f0, f1, f2, f3);
        o.y = pk4_fp8(f4, f5, f6, f7);
        *(uint2*)((unsigned char*)Cv + (size_t)bz * sC + (size_t)gr * N + tile_n + (b >> 1)) = o;
      } else {
        *(f32x4*)((ushort*)Cv + (size_t)bz * sC + (size_t)gr * N + tile_n + (b >> 1)) = d;
      }
    }
  }

  if constexpr (REDUCE == 2) {
    __syncthreads();
    float* sb = (float*)lds;   // [4][256]
#pragma unroll
    for (int nf = 0; nf < 4; ++nf) {
      float s1 = sm2[nf] + __shfl_xor(sm2[nf], 16);
      float Ss = s1 + __shfl_xor(s1, 32);
      if ((lane >> 4) == nf) sb[wr * 256 + ccl[nf]] = Ss;
    }
    __syncthreads();
    if (t < 256) {
      size_t rb = ((size_t)bz * gm + (tile_m >> 8)) * N + tile_n + t;
      red_sum[rb] = sb[t] + sb[256 + t] + sb[512 + t] + sb[768 + t];
    }
  }
  if constexpr (REDUCE == 1) {
    __syncthreads();
    float* mb = (float*)lds;          // [4][256]
    float* sb = (float*)lds + 1024;   // [4][256]
#pragma unroll
    for (int nf = 0; nf < 4; ++nf) {
      float mx = -1e30f;
#pragma unroll
      for (int mi = 0; mi < 4; ++mi)
#pragma unroll
        for (int j = 0; j < 4; ++j) {
          float val = acc[mi][nf][j];
          if (SCALED) val *= scale;
          mx = fmaxf(mx, val);
        }
      float m1 = fmaxf(mx, __shfl_xor(mx, 16));
      float M = fmaxf(m1, __shfl_xor(m1, 32));
      float sm = 0.f;
#pragma unroll
      for (int mi = 0; mi < 4; ++mi)
#pragma unroll
        for (int j = 0; j < 4; ++j) {
          float val = acc[mi][nf][j];
          if (SCALED) val *= scale;
          sm += __expf(val - M);
        }
      float s1 = sm + __shfl_xor(sm, 16);
      float Ss = s1 + __shfl_xor(s1, 32);
      if ((lane >> 4) == nf) {
        mb[wr * 256 + ccl[nf]] = M;
        sb[wr * 256 + ccl[nf]] = Ss;
      }
    }
    __syncthreads();
    if (t < 256) {
      float M = fmaxf(fmaxf(mb[t], mb[256 + t]), fmaxf(mb[512 + t], mb[768 + t]));
      float Ss = sb[t] * __expf(mb[t] - M) + sb[256 + t] * __expf(mb[256 + t] - M) +
                 sb[512 + t] * __expf(mb[512 + t] - M) + sb[768 + t] * __expf(mb[768 + t] - M);
      size_t rb = ((size_t)bz * gm + (tile_m >> 8)) * N + tile_n + t;
      red_max[rb] = M;
      red_sum[rb] = Ss;
    }
  }
}

// c[b,k] = 1024 / sum_ch red_sum[b][ch][k]   (x1024 keeps vs in fp8 range)
__global__ __launch_bounds__(256) void combine_c(
    const float* __restrict__ red_sum, float* __restrict__ cvec, int cols, int nch)
{
  const int b = blockIdx.y;
  const int c = blockIdx.x * 256 + threadIdx.x;
  float Z = 0.f;
  for (int ch = 0; ch < nch; ++ch)
    Z += red_sum[((size_t)b * nch + ch) * cols + c];
  cvec[(size_t)b * cols + c] = 1024.f / Z;
}

// combine partials -> M, 1/Z per (b,col). grid: (cols/256, B)
__global__ __launch_bounds__(256) void colsm_combine(
    const float* __restrict__ red_max, const float* __restrict__ red_sum,
    float* __restrict__ Mv, float* __restrict__ Zinv, int cols, int nch)
{
  const int b = blockIdx.y;
  const int c = blockIdx.x * 256 + threadIdx.x;
  float M = -1e30f, Z = 0.f;
  for (int ch = 0; ch < nch; ++ch) {
    size_t o = ((size_t)b * nch + ch) * cols + c;
    float m = red_max[o], s = red_sum[o];
    float nm = fmaxf(M, m);
    Z = Z * __expf(M - nm) + s * __expf(m - nm);
    M = nm;
  }
  Mv[(size_t)b * cols + c] = M;
  Zinv[(size_t)b * cols + c] = 1.f / Z;
}

// final: out1 = softmax(attn over rows), out0 = attn + residual. attn is bf16.
__global__ __launch_bounds__(256) void final_emit(
    const ushort* __restrict__ attnB, const float* __restrict__ q,
    float* __restrict__ out0, float* __restrict__ out1,
    const float* __restrict__ Mv, const float* __restrict__ Zinv,
    int rows, int cols, int rpc)
{
  const int b = blockIdx.y;
  const int ch = blockIdx.z;
  const size_t base = (size_t)b * rows * cols;
  const int c4 = (blockIdx.x * 256 + threadIdx.x) * 4;
  const int r0 = ch * rpc;
  float M[4], Zi[4];
#pragma unroll
  for (int i = 0; i < 4; ++i) {
    M[i] = Mv[(size_t)b * cols + c4 + i];
    Zi[i] = Zinv[(size_t)b * cols + c4 + i];
  }
  for (int r = r0; r < r0 + rpc; ++r) {
    size_t o = base + (size_t)r * cols + c4;
    ushort4 u = *(const ushort4*)(attnB + o);
    float4 qv = *(const float4*)(q + o);
    float a0 = bf2f(u.x), a1 = bf2f(u.y), a2 = bf2f(u.z), a3 = bf2f(u.w);
    float4 wv, s;
    wv.x = __expf(a0 - M[0]) * Zi[0];
    wv.y = __expf(a1 - M[1]) * Zi[1];
    wv.z = __expf(a2 - M[2]) * Zi[2];
    wv.w = __expf(a3 - M[3]) * Zi[3];
    s.x = a0 + qv.x; s.y = a1 + qv.y; s.z = a2 + qv.z; s.w = a3 + qv.w;
    *(float4*)(out1 + o) = wv;
    *(float4*)(out0 + o) = s;
  }
}

extern "C" void kernel_launch(void* const* d_in, const int* in_sizes, int n_in,
                              void* d_out, int out_size, void* d_ws, size_t ws_size,
                              hipStream_t stream) {
  const float* q  = (const float*)d_in[0];
  const float* k  = (const float*)d_in[1];
  const float* v  = (const float*)d_in[2];
  const float* Wq = (const float*)d_in[3];
  const float* bq = (const float*)d_in[4];
  const float* Wk = (const float*)d_in[5];
  const float* bk = (const float*)d_in[6];
  const float* Wv = (const float*)d_in[7];
  const float* bv = (const float*)d_in[8];
  float* out = (float*)d_out;

  const int B = 8, S = 2048, D = 1024;
  const long BS = (long)B * S;
  const long nQKV = BS * D;        // 16.7M elems
  const long nW = (long)D * D;

  // d_out staging (fp8): qb [0,16M), kb [16,32M), vb [32,48M),
  // Wq8/Wk8/Wv8 @48/49/50M; red_s_sum @64M (512KB); c_s @66M (64KB).
  // final_emit overwrites all of d_out at the end.
  unsigned char* qb8 = (unsigned char*)d_out;
  unsigned char* kb8 = qb8 + nQKV;
  unsigned char* vb8 = kb8 + nQKV;
  unsigned char* Wq8 = (unsigned char*)d_out + (48ull << 20);
  unsigned char* Wk8 = (unsigned char*)d_out + (49ull << 20);
  unsigned char* Wv8 = (unsigned char*)d_out + (50ull << 20);
  float* red_s_sum = (float*)((char*)d_out + (64ull << 20));
  float* c_s       = (float*)((char*)d_out + (66ull << 20));

  // ws: qp8 [0,16M), kp8 [16,32M), vs8 [32,48M),
  //     expS8 [64,96M), attnB bf16 [96,128M), red_f/Mf/Zf @128M+.
  char* ws = (char*)d_ws;
  unsigned char* qp8   = (unsigned char*)ws;
  unsigned char* kp8   = (unsigned char*)(ws + (16ull << 20));
  unsigned char* vs8   = (unsigned char*)(ws + (32ull << 20));
  unsigned char* expS8 = (unsigned char*)(ws + (64ull << 20));
  ushort* attnB        = (ushort*)(ws + (96ull << 20));
  float* red_f_max = (float*)(ws + (128ull << 20));
  float* red_f_sum = (float*)(ws + (129ull << 20));
  float* Mf        = (float*)(ws + (130ull << 20));
  float* Zf        = (float*)(ws + (131ull << 20));

  const int SH = 65536;
  (void)hipFuncSetAttribute(reinterpret_cast<const void*>(&gemmF<1,0,0,0,1,0>),
                            hipFuncAttributeMaxDynamicSharedMemorySize, SH);
  (void)hipFuncSetAttribute(reinterpret_cast<const void*>(&gemmF<2,0,0,0,1,1>),
                            hipFuncAttributeMaxDynamicSharedMemorySize, SH);
  (void)hipFuncSetAttribute(reinterpret_cast<const void*>(&gemmF<0,1,2,1,1,0>),
                            hipFuncAttributeMaxDynamicSharedMemorySize, SH);
  (void)hipFuncSetAttribute(reinterpret_cast<const void*>(&gemmF<0,1,1,0,0,0>),
                            hipFuncAttributeMaxDynamicSharedMemorySize, SH);

  // ---- fp32 -> fp8 conversions (weights; q/k/v), grid-stride ----
  cvt3_fp8<<<dim3(256, 3), 256, 0, stream>>>(
      Wq, Wk, Wv, (uint*)Wq8, (uint*)Wk8, (uint*)Wv8, nW / 16);
  cvt3_fp8<<<dim3(2048, 3), 256, 0, stream>>>(
      q, k, v, (uint*)qb8, (uint*)kb8, (uint*)vb8, nQKV / 16);

  // qp[m][e] = q·Wq + bq (fp8 out)   gm=64, gn=4 -> 256 blocks
  gemmF<1,0,0,0,1,0><<<dim3(64 * 4), 1024, SH, stream>>>(
      qb8, Wq8, qp8, bq, nullptr, nullptr, nullptr, D, D, 0, 0, 0, 1.f, 64, 4);
  gemmF<1,0,0,0,1,0><<<dim3(64 * 4), 1024, SH, stream>>>(
      kb8, Wk8, kp8, bk, nullptr, nullptr, nullptr, D, D, 0, 0, 0, 1.f, 64, 4);
  // expS = exp(qp·kp^T / 1024) (fp8 out) + fused col-sum partials   gm=8, gn=8, b8
  gemmF<0,1,2,1,1,0><<<dim3(8 * 8 * B), 1024, SH, stream>>>(
      qp8, kp8, expS8, nullptr, nullptr, nullptr, red_s_sum,
      S, D, (long)S * D, (long)S * D, (long)S * S, 1.f / 1024.f, 8, 8);
  // c = 1024/colsum
  combine_c<<<dim3(S / 256, B), 256, 0, stream>>>(red_s_sum, c_s, S, 8);

  // vs[b][d][s] = fp8( (Wv·v^T + bv) * c[b][s] )  -- scale_v fused into epilogue
  gemmF<2,0,0,0,1,1><<<dim3(4 * 8 * B), 1024, SH, stream>>>(
      Wv8, vb8, vs8, bv, c_s, nullptr, nullptr,
      S, D, 0, (long)S * D, (long)D * S, 1.f, 4, 8);

  // attn = (expS·vs^T)/1024 (bf16 out) + fused final-softmax pass1  gm=8, gn=4, b8
  gemmF<0,1,1,0,0,0><<<dim3(8 * 4 * B), 1024, SH, stream>>>(
      expS8, vs8, attnB, nullptr, nullptr, red_f_max, red_f_sum,
      D, S, (long)S * S, (long)D * S, (long)S * D, 1.f / 1024.f, 8, 4);

  colsm_combine<<<dim3(D / 256, B), 256, 0, stream>>>(red_f_max, red_f_sum, Mf, Zf, D, 8);
  final_emit<<<dim3(1, B, 128), 256, 0, stream>>>(attnB, q, out, out + nQKV, Mf, Zf, S, D, 16);

  (void)in_sizes; (void)n_in; (void)out_size; (void)ws_size;
}

// Round 22
// 304.404 us; speedup vs baseline: 1.1478x; 1.0032x over previous
//
#include <hip/hip_runtime.h>

typedef __attribute__((ext_vector_type(2))) long lx2;
typedef __attribute__((ext_vector_type(4))) float f32x4;

__device__ __forceinline__ ushort f2bf(float f) {
  union { float f; unsigned u; } x; x.f = f;
  unsigned r = x.u + 0x7FFFu + ((x.u >> 16) & 1u);
  return (ushort)(r >> 16);
}
__device__ __forceinline__ float bf2f(ushort u) {
  union { unsigned u; float f; } x; x.u = ((unsigned)u) << 16;
  return x.f;
}

// ---------------- fp8 e4m3 encode ----------------
#if defined(__has_builtin)
#if __has_builtin(__builtin_amdgcn_cvt_pk_fp8_f32)
#define HAVE_HW_FP8 1
#endif
#endif

#ifdef HAVE_HW_FP8
__device__ __forceinline__ uint pk4_fp8(float f0, float f1, float f2, float f3) {
  int r = __builtin_amdgcn_cvt_pk_fp8_f32(f0, f1, 0, false);
  r = __builtin_amdgcn_cvt_pk_fp8_f32(f2, f3, r, true);
  return (uint)r;
}
#else
// software OCP e4m3fn: value = (8+M)*2^(E-10) for E>=1; M*2^-9 subnormal; max 448.
__device__ __forceinline__ unsigned char f2e4m3(float f) {
  unsigned u = __float_as_uint(f);
  unsigned s = (u >> 24) & 0x80;
  float a = fabsf(f);
  if (a != a) return (unsigned char)(s | 0x7f);
  if (a >= 448.f) return (unsigned char)(s | 0x7e);
  int ei;
  (void)frexpf(a, &ei);
  int E = ei + 6;
  if (E < 1) {
    int ki = (int)rintf(a * 512.f);
    if (ki >= 8) return (unsigned char)(s | 0x08);
    return (unsigned char)(s | ki);
  }
  float q = a * exp2f((float)(10 - E));
  int ki = (int)rintf(q);
  if (ki >= 16) { E++; ki = 8; }
  if (E > 15 || (E == 15 && ki > 14)) return (unsigned char)(s | 0x7e);
  return (unsigned char)(s | (E << 3) | (ki - 8));
}
__device__ __forceinline__ uint pk4_fp8(float f0, float f1, float f2, float f3) {
  return (uint)f2e4m3(f0) | ((uint)f2e4m3(f1) << 8) |
         ((uint)f2e4m3(f2) << 16) | ((uint)f2e4m3(f3) << 24);
}
#endif

__device__ __forceinline__ void gload_lds16(const void* g, void* l) {
  __builtin_amdgcn_global_load_lds(
      (const __attribute__((address_space(1))) void*)g,
      (__attribute__((address_space(3))) void*)l, 16, 0, 0);
}

// ------- fp32 -> fp8, grid-stride software-pipelined -------
__global__ __launch_bounds__(256) void cvt3_fp8(
    const float* __restrict__ s0, const float* __restrict__ s1,
    const float* __restrict__ s2, uint* __restrict__ d0,
    uint* __restrict__ d1, uint* __restrict__ d2, long n16) {
  const float4* s = (const float4*)(blockIdx.y == 0 ? s0 : (blockIdx.y == 1 ? s1 : s2));
  uint* d = blockIdx.y == 0 ? d0 : (blockIdx.y == 1 ? d1 : d2);
  long i = (long)blockIdx.x * 256 + threadIdx.x;
  const long stride = (long)gridDim.x * 256;
  if (i >= n16) return;
  float4 a0 = s[i * 4], a1 = s[i * 4 + 1], a2 = s[i * 4 + 2], a3 = s[i * 4 + 3];
  for (;;) {
    const long inext = i + stride;
    const bool more = inext < n16;
    float4 b0, b1, b2, b3;
    if (more) { b0 = s[inext * 4]; b1 = s[inext * 4 + 1];
                b2 = s[inext * 4 + 2]; b3 = s[inext * 4 + 3]; }
    uint4 o;
    o.x = pk4_fp8(a0.x, a0.y, a0.z, a0.w);
    o.y = pk4_fp8(a1.x, a1.y, a1.z, a1.w);
    o.z = pk4_fp8(a2.x, a2.y, a2.z, a2.w);
    o.w = pk4_fp8(a3.x, a3.y, a3.z, a3.w);
    *(uint4*)(d + i * 4) = o;
    if (!more) break;
    i = inext;
    a0 = b0; a1 = b1; a2 = b2; a3 = b3;
  }
}

// ============ 256x256 16-wave fp8 GEMM (B^T form), 1 barrier / K-tile ============
// C[m,n] = f((sum_k A[m,k]*B[n,k])*(SCALED?scale:1) + bias [* cscale_col]),
// f=exp if EXPOUT. CSCALE: epilogue multiplies by cscale[bz*N+col].
// DUAL: bz selects pointer-set {A,B,bias,Cv} (0) or {A2,B2,bias2,Cv2} (1) --
// merges two independent same-shape GEMMs into one dispatch (2x occupancy).
template<int BIAS_MODE, int SCALED, int REDUCE, int EXPOUT, int OUT_FP8, int CSCALE, int DUAL>
__global__ __launch_bounds__(1024, 4) void gemmF(
    const unsigned char* __restrict__ A, const unsigned char* __restrict__ B,
    void* __restrict__ Cv, const float* __restrict__ bias,
    const unsigned char* __restrict__ A2, const unsigned char* __restrict__ B2,
    void* __restrict__ Cv2, const float* __restrict__ bias2,
    const float* __restrict__ cscale,
    float* __restrict__ red_max, float* __restrict__ red_sum,
    int N, int K, long sA, long sB, long sC, float scale, int gm, int gn)
{
  extern __shared__ unsigned char lds[];   // 65536 B

  // ---- tile decode: bijective XCD swizzle + banded order ----
  const int nwg = gridDim.x;
  const int wg = blockIdx.x;
  const int cpx = nwg >> 3;
  const int wid_ = (wg & 7) * cpx + (wg >> 3);
  const int tiles = gm * gn;
  const int bz = wid_ / tiles;
  const int t2 = wid_ - bz * tiles;
  const int band = t2 / (gm << 2);
  const int r2 = t2 - band * (gm << 2);
  const int tile_m = (r2 >> 2) * 256;
  const int tile_n = ((band << 2) + (r2 & 3)) * 256;

  const unsigned char* Ab;
  const unsigned char* Bb;
  const float* biasp;
  void* Cvp;
  if (DUAL && bz == 1) { Ab = A2; Bb = B2; biasp = bias2; Cvp = Cv2; }
  else { Ab = A + (size_t)bz * sA; Bb = B + (size_t)bz * sB; biasp = bias; Cvp = Cv; }

  const int t = threadIdx.x;
  const int lane = t & 63;
  const int w = t >> 6;        // 0..15
  const int wr = w >> 2;       // 0..3
  const int wc = w & 3;        // 0..3

  f32x4 acc[4][4] = {};

#define STAGE(c, k0)                                                                   \
  do {                                                                                 \
    gload_lds16(Ab + (size_t)(tile_m + w * 16 + (lane & 15)) * K + (k0) +              \
                    (lane >> 4) * 16,                                                  \
                lds + (c) * 32768 + w * 1024);                                         \
    gload_lds16(Bb + (size_t)(tile_n + w * 16 + (lane & 15)) * K + (k0) +              \
                    (lane >> 4) * 16,                                                  \
                lds + (c) * 32768 + 16384 + w * 1024);                                 \
  } while (0)

  // ---- prologue ----
  STAGE(0, 0);

  const int KT = K >> 6;
  for (int tt = 0; tt < KT; ++tt) {
    const int c = tt & 1;
    asm volatile("s_waitcnt vmcnt(0)" ::: "memory");   // tile tt's 2 stages (1-tile dist)
    __builtin_amdgcn_s_barrier();                      // publish all waves' stages
    if (tt + 1 < KT) STAGE(c ^ 1, (tt + 1) << 6);
    lx2 aA[4], bB[4];
#pragma unroll
    for (int mi = 0; mi < 4; ++mi)
      aA[mi] = *(const lx2*)(lds + c * 32768 + (wr * 4 + mi) * 1024 + lane * 16);
#pragma unroll
    for (int nf = 0; nf < 4; ++nf)
      bB[nf] = *(const lx2*)(lds + c * 32768 + 16384 + (wc * 4 + nf) * 1024 + lane * 16);
    asm volatile("s_waitcnt lgkmcnt(0)" ::: "memory");
    __builtin_amdgcn_sched_barrier(0);
    __builtin_amdgcn_s_setprio(1);
#pragma unroll
    for (int kk = 0; kk < 2; ++kk)
#pragma unroll
      for (int mi = 0; mi < 4; ++mi)
#pragma unroll
        for (int nf = 0; nf < 4; ++nf)
          acc[mi][nf] = __builtin_amdgcn_mfma_f32_16x16x32_fp8_fp8(
              aA[mi][kk], bB[nf][kk], acc[mi][nf], 0, 0, 0);
    __builtin_amdgcn_s_setprio(0);
  }
#undef STAGE

  // ---- epilogue: 2 half-passes (128 rows) via LDS bf16, swizzled ----
  float sm2[4] = {0.f, 0.f, 0.f, 0.f};
  const int g5 = ((lane >> 4) & 3) << 5;
  int ccl[4]; float bcn[4]; float csc[4];
#pragma unroll
  for (int nf = 0; nf < 4; ++nf) {
    ccl[nf] = wc * 64 + nf * 16 + (lane & 15);
    bcn[nf] = (BIAS_MODE == 1) ? biasp[tile_n + ccl[nf]] : 0.f;
    csc[nf] = (CSCALE) ? cscale[(size_t)bz * N + tile_n + ccl[nf]] : 1.f;
  }
#pragma unroll
  for (int h = 0; h < 2; ++h) {
    __syncthreads();
    if ((wr >> 1) == h) {
#pragma unroll
      for (int mi = 0; mi < 4; ++mi) {
#pragma unroll
        for (int j = 0; j < 4; ++j) {
          const int row = (wr & 1) * 64 + mi * 16 + ((lane >> 4) << 2) + j;  // 0..127
          float bcr = (BIAS_MODE == 2) ? biasp[tile_m + h * 128 + row] : 0.f;
#pragma unroll
          for (int nf = 0; nf < 4; ++nf) {
            float val = acc[mi][nf][j];
            if (SCALED) val *= scale;
            if (BIAS_MODE == 1) val += bcn[nf];
            else if (BIAS_MODE == 2) val += bcr;
            if (CSCALE) val *= csc[nf];
            if (EXPOUT) val = __expf(val);
            if (REDUCE == 2) sm2[nf] += val;
            *(ushort*)(lds + row * 512 + ((ccl[nf] * 2) ^ g5)) = f2bf(val);
          }
        }
      }
    }
    __syncthreads();
    // coalesced flush: 4 passes x 1024 thr x 16B LDS
#pragma unroll
    for (int p = 0; p < 4; ++p) {
      int off = p * 16384 + t * 16;
      int row = off >> 9;
      int b = off & 511;
      int bs = b ^ (((row >> 2) & 3) << 5);
      f32x4 d = *(const f32x4*)(lds + row * 512 + bs);
      const int gr = tile_m + h * 128 + row;
      if (OUT_FP8) {
        const uint* dw = (const uint*)&d;
        float f0 = bf2f((ushort)(dw[0] & 0xffff)), f1 = bf2f((ushort)(dw[0] >> 16));
        float f2 = bf2f((ushort)(dw[1] & 0xffff)), f3 = bf2f((ushort)(dw[1] >> 16));
        float f4 = bf2f((ushort)(dw[2] & 0xffff)), f5 = bf2f((ushort)(dw[2] >> 16));
        float f6 = bf2f((ushort)(dw[3] & 0xffff)), f7 = bf2f((ushort)(dw[3] >> 16));
        uint2 o;
        o.x = pk4_fp8(f0, f1, f2, f3);
        o.y = pk4_fp8(f4, f5, f6, f7);
        *(uint2*)((unsigned char*)Cvp + (size_t)bz * sC * (DUAL ? 0 : 1) + (size_t)gr * N + tile_n + (b >> 1)) = o;
      } else {
        *(f32x4*)((ushort*)Cvp + (size_t)bz * sC * (DUAL ? 0 : 1) + (size_t)gr * N + tile_n + (b >> 1)) = d;
      }
    }
  }

  if constexpr (REDUCE == 2) {
    __syncthreads();
    float* sb = (float*)lds;   // [4][256]
#pragma unroll
    for (int nf = 0; nf < 4; ++nf) {
      float s1 = sm2[nf] + __shfl_xor(sm2[nf], 16);
      float Ss = s1 + __shfl_xor(s1, 32);
      if ((lane >> 4) == nf) sb[wr * 256 + ccl[nf]] = Ss;
    }
    __syncthreads();
    if (t < 256) {
      size_t rb = ((size_t)bz * gm + (tile_m >> 8)) * N + tile_n + t;
      red_sum[rb] = sb[t] + sb[256 + t] + sb[512 + t] + sb[768 + t];
    }
  }
  if constexpr (REDUCE == 1) {
    __syncthreads();
    float* mb = (float*)lds;          // [4][256]
    float* sb = (float*)lds + 1024;   // [4][256]
#pragma unroll
    for (int nf = 0; nf < 4; ++nf) {
      float mx = -1e30f;
#pragma unroll
      for (int mi = 0; mi < 4; ++mi)
#pragma unroll
        for (int j = 0; j < 4; ++j) {
          float val = acc[mi][nf][j];
          if (SCALED) val *= scale;
          mx = fmaxf(mx, val);
        }
      float m1 = fmaxf(mx, __shfl_xor(mx, 16));
      float M = fmaxf(m1, __shfl_xor(m1, 32));
      float sm = 0.f;
#pragma unroll
      for (int mi = 0; mi < 4; ++mi)
#pragma unroll
        for (int j = 0; j < 4; ++j) {
          float val = acc[mi][nf][j];
          if (SCALED) val *= scale;
          sm += __expf(val - M);
        }
      float s1 = sm + __shfl_xor(sm, 16);
      float Ss = s1 + __shfl_xor(s1, 32);
      if ((lane >> 4) == nf) {
        mb[wr * 256 + ccl[nf]] = M;
        sb[wr * 256 + ccl[nf]] = Ss;
      }
    }
    __syncthreads();
    if (t < 256) {
      float M = fmaxf(fmaxf(mb[t], mb[256 + t]), fmaxf(mb[512 + t], mb[768 + t]));
      float Ss = sb[t] * __expf(mb[t] - M) + sb[256 + t] * __expf(mb[256 + t] - M) +
                 sb[512 + t] * __expf(mb[512 + t] - M) + sb[768 + t] * __expf(mb[768 + t] - M);
      size_t rb = ((size_t)bz * gm + (tile_m >> 8)) * N + tile_n + t;
      red_max[rb] = M;
      red_sum[rb] = Ss;
    }
  }
}

// c[b,k] = 1024 / sum_ch red_sum[b][ch][k]   (x1024 keeps vs in fp8 range)
__global__ __launch_bounds__(256) void combine_c(
    const float* __restrict__ red_sum, float* __restrict__ cvec, int cols, int nch)
{
  const int b = blockIdx.y;
  const int c = blockIdx.x * 256 + threadIdx.x;
  float Z = 0.f;
  for (int ch = 0; ch < nch; ++ch)
    Z += red_sum[((size_t)b * nch + ch) * cols + c];
  cvec[(size_t)b * cols + c] = 1024.f / Z;
}

// combine partials -> M, 1/Z per (b,col). grid: (cols/256, B)
__global__ __launch_bounds__(256) void colsm_combine(
    const float* __restrict__ red_max, const float* __restrict__ red_sum,
    float* __restrict__ Mv, float* __restrict__ Zinv, int cols, int nch)
{
  const int b = blockIdx.y;
  const int c = blockIdx.x * 256 + threadIdx.x;
  float M = -1e30f, Z = 0.f;
  for (int ch = 0; ch < nch; ++ch) {
    size_t o = ((size_t)b * nch + ch) * cols + c;
    float m = red_max[o], s = red_sum[o];
    float nm = fmaxf(M, m);
    Z = Z * __expf(M - nm) + s * __expf(m - nm);
    M = nm;
  }
  Mv[(size_t)b * cols + c] = M;
  Zinv[(size_t)b * cols + c] = 1.f / Z;
}

// final: out1 = softmax(attn over rows), out0 = attn + residual. attn is bf16.
__global__ __launch_bounds__(256) void final_emit(
    const ushort* __restrict__ attnB, const float* __restrict__ q,
    float* __restrict__ out0, float* __restrict__ out1,
    const float* __restrict__ Mv, const float* __restrict__ Zinv,
    int rows, int cols, int rpc)
{
  const int b = blockIdx.y;
  const int ch = blockIdx.z;
  const size_t base = (size_t)b * rows * cols;
  const int c4 = (blockIdx.x * 256 + threadIdx.x) * 4;
  const int r0 = ch * rpc;
  float M[4], Zi[4];
#pragma unroll
  for (int i = 0; i < 4; ++i) {
    M[i] = Mv[(size_t)b * cols + c4 + i];
    Zi[i] = Zinv[(size_t)b * cols + c4 + i];
  }
  for (int r = r0; r < r0 + rpc; ++r) {
    size_t o = base + (size_t)r * cols + c4;
    ushort4 u = *(const ushort4*)(attnB + o);
    float4 qv = *(const float4*)(q + o);
    float a0 = bf2f(u.x), a1 = bf2f(u.y), a2 = bf2f(u.z), a3 = bf2f(u.w);
    float4 wv, s;
    wv.x = __expf(a0 - M[0]) * Zi[0];
    wv.y = __expf(a1 - M[1]) * Zi[1];
    wv.z = __expf(a2 - M[2]) * Zi[2];
    wv.w = __expf(a3 - M[3]) * Zi[3];
    s.x = a0 + qv.x; s.y = a1 + qv.y; s.z = a2 + qv.z; s.w = a3 + qv.w;
    *(float4*)(out1 + o) = wv;
    *(float4*)(out0 + o) = s;
  }
}

extern "C" void kernel_launch(void* const* d_in, const int* in_sizes, int n_in,
                              void* d_out, int out_size, void* d_ws, size_t ws_size,
                              hipStream_t stream) {
  const float* q  = (const float*)d_in[0];
  const float* k  = (const float*)d_in[1];
  const float* v  = (const float*)d_in[2];
  const float* Wq = (const float*)d_in[3];
  const float* bq = (const float*)d_in[4];
  const float* Wk = (const float*)d_in[5];
  const float* bk = (const float*)d_in[6];
  const float* Wv = (const float*)d_in[7];
  const float* bv = (const float*)d_in[8];
  float* out = (float*)d_out;

  const int B = 8, S = 2048, D = 1024;
  const long BS = (long)B * S;
  const long nQKV = BS * D;        // 16.7M elems
  const long nW = (long)D * D;

  // d_out staging (fp8): qb [0,16M), kb [16,32M), vb [32,48M),
  // Wq8/Wk8/Wv8 @48/49/50M; red_s_sum @64M (512KB); c_s @66M (64KB).
  // final_emit overwrites all of d_out at the end.
  unsigned char* qb8 = (unsigned char*)d_out;
  unsigned char* kb8 = qb8 + nQKV;
  unsigned char* vb8 = kb8 + nQKV;
  unsigned char* Wq8 = (unsigned char*)d_out + (48ull << 20);
  unsigned char* Wk8 = (unsigned char*)d_out + (49ull << 20);
  unsigned char* Wv8 = (unsigned char*)d_out + (50ull << 20);
  float* red_s_sum = (float*)((char*)d_out + (64ull << 20));
  float* c_s       = (float*)((char*)d_out + (66ull << 20));

  // ws: qp8 [0,16M), kp8 [16,32M), vs8 [32,48M),
  //     expS8 [64,96M), attnB bf16 [96,128M), red_f/Mf/Zf @128M+.
  char* ws = (char*)d_ws;
  unsigned char* qp8   = (unsigned char*)ws;
  unsigned char* kp8   = (unsigned char*)(ws + (16ull << 20));
  unsigned char* vs8   = (unsigned char*)(ws + (32ull << 20));
  unsigned char* expS8 = (unsigned char*)(ws + (64ull << 20));
  ushort* attnB        = (ushort*)(ws + (96ull << 20));
  float* red_f_max = (float*)(ws + (128ull << 20));
  float* red_f_sum = (float*)(ws + (129ull << 20));
  float* Mf        = (float*)(ws + (130ull << 20));
  float* Zf        = (float*)(ws + (131ull << 20));

  const int SH = 65536;
  (void)hipFuncSetAttribute(reinterpret_cast<const void*>(&gemmF<1,0,0,0,1,0,1>),
                            hipFuncAttributeMaxDynamicSharedMemorySize, SH);
  (void)hipFuncSetAttribute(reinterpret_cast<const void*>(&gemmF<2,0,0,0,1,1,0>),
                            hipFuncAttributeMaxDynamicSharedMemorySize, SH);
  (void)hipFuncSetAttribute(reinterpret_cast<const void*>(&gemmF<0,1,2,1,1,0,0>),
                            hipFuncAttributeMaxDynamicSharedMemorySize, SH);
  (void)hipFuncSetAttribute(reinterpret_cast<const void*>(&gemmF<0,1,1,0,0,0,0>),
                            hipFuncAttributeMaxDynamicSharedMemorySize, SH);

  // ---- fp32 -> fp8 conversions (weights; q/k/v), grid-stride ----
  cvt3_fp8<<<dim3(256, 3), 256, 0, stream>>>(
      Wq, Wk, Wv, (uint*)Wq8, (uint*)Wk8, (uint*)Wv8, nW / 16);
  cvt3_fp8<<<dim3(2048, 3), 256, 0, stream>>>(
      q, k, v, (uint*)qb8, (uint*)kb8, (uint*)vb8, nQKV / 16);

  // qp & kp in ONE dispatch (DUAL): 512 blocks = 2/CU-capacity fill
  gemmF<1,0,0,0,1,0,1><<<dim3(2 * 64 * 4), 1024, SH, stream>>>(
      qb8, Wq8, qp8, bq, kb8, Wk8, kp8, bk,
      nullptr, nullptr, nullptr, D, D, 0, 0, 0, 1.f, 64, 4);
  // expS = exp(qp·kp^T / 1024) (fp8 out) + fused col-sum partials   gm=8, gn=8, b8
  gemmF<0,1,2,1,1,0,0><<<dim3(8 * 8 * B), 1024, SH, stream>>>(
      qp8, kp8, expS8, nullptr, nullptr, nullptr, nullptr, nullptr, nullptr,
      nullptr, red_s_sum,
      S, D, (long)S * D, (long)S * D, (long)S * S, 1.f / 1024.f, 8, 8);
  // c = 1024/colsum
  combine_c<<<dim3(S / 256, B), 256, 0, stream>>>(red_s_sum, c_s, S, 8);

  // vs[b][d][s] = fp8( (Wv·v^T + bv) * c[b][s] )  -- scale_v fused into epilogue
  gemmF<2,0,0,0,1,1,0><<<dim3(4 * 8 * B), 1024, SH, stream>>>(
      Wv8, vb8, vs8, bv, nullptr, nullptr, nullptr, nullptr, c_s, nullptr, nullptr,
      S, D, 0, (long)S * D, (long)D * S, 1.f, 4, 8);

  // attn = (expS·vs^T)/1024 (bf16 out) + fused final-softmax pass1  gm=8, gn=4, b8
  gemmF<0,1,1,0,0,0,0><<<dim3(8 * 4 * B), 1024, SH, stream>>>(
      expS8, vs8, attnB, nullptr, nullptr, nullptr, nullptr, nullptr, nullptr,
      red_f_max, red_f_sum,
      D, S, (long)S * S, (long)D * S, (long)S * D, 1.f / 1024.f, 8, 4);

  colsm_combine<<<dim3(D / 256, B), 256, 0, stream>>>(red_f_max, red_f_sum, Mf, Zf, D, 8);
  final_emit<<<dim3(1, B, 128), 256, 0, stream>>>(attnB, q, out, out + nQKV, Mf, Zf, S, D, 16);

  (void)in_sizes; (void)n_in; (void)out_size; (void)ws_size;
}